// Round 11
// baseline (289.862 us; speedup 1.0000x reference)
//
#include <hip/hip_runtime.h>
#include <hip/hip_bf16.h>
#include <stdint.h>

// Problem constants: B=2, N=2048, K=48, H=128, 3H=384, FF=512
// Persistent pipelined blocks; split x-tile (E=hE half, G=gather half), pitch 136.
#define MP 136      // tile/mid pitch (bf16): 68 dwords (68%32=4, 2-way only = free)
#define FFP 520     // ffn mid pitch
#define EPIP 132

typedef __attribute__((ext_vector_type(8))) short bf16x8;
typedef __attribute__((ext_vector_type(4))) float f32x4;

__device__ __forceinline__ f32x4 mfma16(bf16x8 a, bf16x8 b, f32x4 c) {
  return __builtin_amdgcn_mfma_f32_16x16x32_bf16(a, b, c, 0, 0, 0);
}

__device__ __forceinline__ uint16_t f2b(float f) {
  union { __hip_bfloat16 h; uint16_t u; } v;
  v.h = __float2bfloat16(f);
  return v.u;
}
__device__ __forceinline__ float b2f(uint16_t h) {
  union { uint32_t u; float f; } v; v.u = ((uint32_t)h) << 16;
  return v.f;
}
__device__ __forceinline__ uint32_t pk2f(float a, float b) {
  union { __hip_bfloat162 h; uint32_t u; } v;
  v.h = __float22bfloat162_rn(make_float2(a, b));
  return v.u;
}
__device__ __forceinline__ float gelu_f(float x) {
  float u = __builtin_fmaf(x * x, 0.044715f, 1.0f);
  float e = __builtin_amdgcn_exp2f(-2.302585093f * x * u);
  return x * __builtin_amdgcn_rcpf(1.0f + e);
}
__device__ __forceinline__ int div48(int e) {  // e < 196608
  return (int)((((unsigned)e >> 4) * 0xAAABu) >> 17);
}

// ---------------- prep: bf16 h_V + transposed bf16 weights ----------------
__global__ __launch_bounds__(256) void k_prep(
    const float* __restrict__ hV,
    const float* __restrict__ W1, const float* __restrict__ W2, const float* __restrict__ W3,
    const float* __restrict__ WdIn, const float* __restrict__ WdOut,
    const float* __restrict__ W11, const float* __restrict__ W12, const float* __restrict__ W13,
    uint16_t* __restrict__ hVb,
    uint16_t* __restrict__ W1t, uint16_t* __restrict__ W2t, uint16_t* __restrict__ W3t,
    uint16_t* __restrict__ WdInT, uint16_t* __restrict__ WdOutT,
    uint16_t* __restrict__ W11t, uint16_t* __restrict__ W12t, uint16_t* __restrict__ W13t) {
  int i = blockIdx.x * 256 + threadIdx.x;
  if (i < 524288) { hVb[i] = f2b(hV[i]); return; }
  int j = i - 524288;
  if (j < 49152) { int n = j / 384, k = j - n * 384; W1t[j] = f2b(W1[k * 128 + n]); return; }
  j -= 49152;
  if (j < 16384) { int n = j >> 7, k = j & 127; W2t[j] = f2b(W2[k * 128 + n]); return; }
  j -= 16384;
  if (j < 16384) { int n = j >> 7, k = j & 127; W3t[j] = f2b(W3[k * 128 + n]); return; }
  j -= 16384;
  if (j < 65536) { int n = j >> 7, k = j & 127; WdInT[j] = f2b(WdIn[k * 512 + n]); return; }
  j -= 65536;
  if (j < 65536) { int n = j >> 9, k = j & 511; WdOutT[j] = f2b(WdOut[k * 128 + n]); return; }
  j -= 65536;
  if (j < 49152) { int n = j / 384, k = j - n * 384; W11t[j] = f2b(W11[k * 128 + n]); return; }
  j -= 49152;
  if (j < 16384) { int n = j >> 7, k = j & 127; W12t[j] = f2b(W12[k * 128 + n]); return; }
  j -= 16384;
  if (j < 16384) { int n = j >> 7, k = j & 127; W13t[j] = f2b(W13[k * 128 + n]); return; }
}

// ------- k_vec: C[i][n] = sum_{k<128} Xb[i][k]*Wt[n][k] + bias[n] -------
__global__ __launch_bounds__(256) void k_vec(
    const uint16_t* __restrict__ Xb, const uint16_t* __restrict__ Wt,
    const float* __restrict__ bias, float* __restrict__ C) {
  const int tid = threadIdx.x;
  const int lane = tid & 63, w = tid >> 6, l15 = lane & 15, lg = lane >> 4;
  const int row0 = blockIdx.x * 64 + w * 16;
  f32x4 acc[8] = {};
#pragma unroll
  for (int ks = 0; ks < 4; ++ks) {
    bf16x8 a = *(const bf16x8*)(Xb + (row0 + l15) * 128 + ks * 32 + lg * 8);
#pragma unroll
    for (int j = 0; j < 8; ++j) {
      bf16x8 bb = *(const bf16x8*)(Wt + (j * 16 + l15) * 384 + ks * 32 + lg * 8);
      acc[j] = mfma16(a, bb, acc[j]);
    }
  }
#pragma unroll
  for (int j = 0; j < 8; ++j) {
    float bs = bias[j * 16 + l15];
#pragma unroll
    for (int r = 0; r < 4; ++r)
      C[(row0 + lg * 4 + r) * 128 + j * 16 + l15] = acc[j][r] + bs;
  }
}

// ===== MFMA layer macros over split tiles (pitch MP), MM = m-tile count =====
#define LAYER256S(WT, XE, XG, ACC, MM)                                              \
  do {                                                                              \
    const uint16_t* wr0_ = (WT) + (w * 32 + l15) * 384 + 128 + lg * 8;              \
    const uint16_t* wr1_ = wr0_ + 16 * 384;                                         \
    _Pragma("unroll") for (int ks = 0; ks < 8; ++ks) {                              \
      const uint16_t* xb_ = (ks < 4) ? (XE) : (XG);                                 \
      int kk_ = ks & 3;                                                             \
      bf16x8 bA_ = *(const bf16x8*)(wr0_ + ks * 32);                                \
      bf16x8 bB_ = *(const bf16x8*)(wr1_ + ks * 32);                                \
      _Pragma("unroll") for (int m = 0; m < (MM); ++m) {                            \
        bf16x8 a_ = *(const bf16x8*)(xb_ + (m * 16 + l15) * MP + kk_ * 32 + lg * 8);\
        ACC[m][0] = mfma16(a_, bA_, ACC[m][0]);                                     \
        ACC[m][1] = mfma16(a_, bB_, ACC[m][1]);                                     \
      }                                                                             \
    }                                                                               \
  } while (0)

#define LAYER128S(WT, ASRC, ACC, MM)                                                \
  do {                                                                              \
    const uint16_t* wr0_ = (WT) + (w * 32 + l15) * 128 + lg * 8;                    \
    const uint16_t* wr1_ = wr0_ + 16 * 128;                                         \
    _Pragma("unroll") for (int ks = 0; ks < 4; ++ks) {                              \
      bf16x8 bA_ = *(const bf16x8*)(wr0_ + ks * 32);                                \
      bf16x8 bB_ = *(const bf16x8*)(wr1_ + ks * 32);                                \
      _Pragma("unroll") for (int m = 0; m < (MM); ++m) {                            \
        bf16x8 a_ = *(const bf16x8*)((ASRC) + (m * 16 + l15) * MP + ks * 32 + lg * 8); \
        ACC[m][0] = mfma16(a_, bA_, ACC[m][0]);                                     \
        ACC[m][1] = mfma16(a_, bB_, ACC[m][1]);                                     \
      }                                                                              \
    }                                                                               \
  } while (0)

#define GSTOREM(ACC, BIAS, DST, MM)                                                 \
  do {                                                                              \
    float bA_ = (BIAS)[w * 32 + l15];                                               \
    float bB_ = (BIAS)[w * 32 + 16 + l15];                                          \
    _Pragma("unroll") for (int m = 0; m < (MM); ++m)                                \
    _Pragma("unroll") for (int r = 0; r < 4; ++r) {                                 \
      int row_ = m * 16 + lg * 4 + r;                                               \
      (DST)[row_ * MP + w * 32 + l15] = f2b(gelu_f(ACC[m][0][r] + bA_));            \
      (DST)[row_ * MP + w * 32 + 16 + l15] = f2b(gelu_f(ACC[m][1][r] + bB_));       \
    }                                                                               \
  } while (0)

#define GSTORE0M(ACC, DST, MM)                                                      \
  do {                                                                              \
    _Pragma("unroll") for (int m = 0; m < (MM); ++m)                                \
    _Pragma("unroll") for (int r = 0; r < 4; ++r) {                                 \
      int row_ = m * 16 + lg * 4 + r;                                               \
      (DST)[row_ * MP + w * 32 + l15] = f2b(gelu_f(ACC[m][0][r]));                  \
      (DST)[row_ * MP + w * 32 + 16 + l15] = f2b(gelu_f(ACC[m][1][r]));             \
    }                                                                               \
  } while (0)

// ---------------- K1: node MLP + masked sum + LN1 (M=48, pipelined 8 tiles) ----------------
// LDS: xE0 @0 | xE1 @13056 | xG0 @26112 | xG1 @39168 | mid @52224 | dh @65280 = 65792 B
__global__ __launch_bounds__(256, 2) void k_node(
    const float* __restrict__ hV, const float* __restrict__ hE,
    const int* __restrict__ eidx, const float* __restrict__ maskA,
    const float* __restrict__ bias2, const float* __restrict__ bias3,
    const float* __restrict__ g1, const float* __restrict__ be1,
    const uint16_t* __restrict__ hVb, const float* __restrict__ C1,
    const uint16_t* __restrict__ W1t, const uint16_t* __restrict__ W2t,
    const uint16_t* __restrict__ W3t,
    float* __restrict__ hV1, uint16_t* __restrict__ hV1b) {
  __shared__ __align__(16) unsigned char lds[65792];
  uint16_t* xE0 = (uint16_t*)lds;
  uint16_t* xE1 = (uint16_t*)(lds + 13056);
  uint16_t* xG0 = (uint16_t*)(lds + 26112);
  uint16_t* xG1 = (uint16_t*)(lds + 39168);
  uint16_t* mid = (uint16_t*)(lds + 52224);
  float* dh = (float*)(lds + 65280);

  const int tid = threadIdx.x;
  const int lane = tid & 63;
  const int w = tid >> 6;
  const int l15 = lane & 15;
  const int lg = lane >> 4;

  float4 fE[6];
  uint4 gV[3];

#define NLOAD48(TB)                                                                 \
  _Pragma("unroll") for (int i_ = 0; i_ < 3; ++i_) {                                \
    int c_ = tid + i_ * 256, row_ = c_ >> 4, p_ = c_ & 15;                          \
    const float* sE_ = hE + (size_t)((TB) + row_) * 128 + p_ * 8;                   \
    fE[i_ * 2] = *(const float4*)sE_;                                               \
    fE[i_ * 2 + 1] = *(const float4*)(sE_ + 4);                                     \
    int e_ = (TB) + row_;                                                           \
    int nb_ = ((e_ >= 98304) ? 2048 : 0) + eidx[e_];                                \
    gV[i_] = *(const uint4*)(hVb + (size_t)nb_ * 128 + p_ * 8);                     \
  }

#define NWRITE48(XE, XG)                                                            \
  _Pragma("unroll") for (int i_ = 0; i_ < 3; ++i_) {                                \
    int c_ = tid + i_ * 256, row_ = c_ >> 4, p_ = c_ & 15;                          \
    uint4 v_ = make_uint4(pk2f(fE[i_ * 2].x, fE[i_ * 2].y),                         \
                          pk2f(fE[i_ * 2].z, fE[i_ * 2].w),                         \
                          pk2f(fE[i_ * 2 + 1].x, fE[i_ * 2 + 1].y),                 \
                          pk2f(fE[i_ * 2 + 1].z, fE[i_ * 2 + 1].w));                \
    *(uint4*)((XE) + row_ * MP + p_ * 8) = v_;                                      \
    *(uint4*)((XG) + row_ * MP + p_ * 8) = gV[i_];                                  \
  }

  uint16_t *xEc = xE0, *xEn = xE1, *xGc = xG0, *xGn = xG1;

  NLOAD48(blockIdx.x * 48);
  NWRITE48(xEc, xGc);
  __syncthreads();

  for (int t = 0; t < 8; ++t) {
    const int tile = t * 512 + blockIdx.x;   // = node
    const int tbase = tile * 48;
    if (t < 7) NLOAD48((tile + 512) * 48);

    f32x4 acc1[3][2];
    {
      float c0 = C1[(size_t)tile * 128 + w * 32 + l15];
      float c1 = C1[(size_t)tile * 128 + w * 32 + 16 + l15];
#pragma unroll
      for (int m = 0; m < 3; ++m) {
        acc1[m][0] = (f32x4){c0, c0, c0, c0};
        acc1[m][1] = (f32x4){c1, c1, c1, c1};
      }
    }
    LAYER256S(W1t, xEc, xGc, acc1, 3);
    GSTORE0M(acc1, mid, 3);
    __syncthreads();

    f32x4 acc2[3][2] = {};
    LAYER128S(W2t, mid, acc2, 3);
    __syncthreads();               // all mid reads done before overwrite
    GSTOREM(acc2, bias2, mid, 3);
    __syncthreads();

    f32x4 acc3[3][2] = {};
    LAYER128S(W3t, mid, acc3, 3);
    if (t < 7) NWRITE48(xEn, xGn);

    // masked column sums over the 48 rows
    {
      float bA = bias3[w * 32 + l15];
      float bB = bias3[w * 32 + 16 + l15];
      float s0 = 0.f, s1 = 0.f;
#pragma unroll
      for (int m = 0; m < 3; ++m)
#pragma unroll
        for (int r = 0; r < 4; ++r) {
          int row = m * 16 + lg * 4 + r;
          float mk = maskA[tbase + row];
          s0 += (acc3[m][0][r] + bA) * mk;
          s1 += (acc3[m][1][r] + bB) * mk;
        }
      s0 += __shfl_xor(s0, 16); s0 += __shfl_xor(s0, 32);
      s1 += __shfl_xor(s1, 16); s1 += __shfl_xor(s1, 32);
      if (lg == 0) { dh[w * 32 + l15] = s0; dh[w * 32 + 16 + l15] = s1; }
    }
    __syncthreads();

    if (w == 0) {
      const float inv = 1.0f / 30.0f;
      float x0 = hV[(size_t)tile * 128 + lane] + dh[lane] * inv;
      float x1 = hV[(size_t)tile * 128 + 64 + lane] + dh[64 + lane] * inv;
      float s = x0 + x1, q = x0 * x0 + x1 * x1;
#pragma unroll
      for (int off = 1; off < 64; off <<= 1) {
        s += __shfl_xor(s, off);
        q += __shfl_xor(q, off);
      }
      float mean = s * (1.0f / 128.0f);
      float var = q * (1.0f / 128.0f) - mean * mean;
      float rstd = rsqrtf(var + 1e-5f);
      float y0 = (x0 - mean) * rstd * g1[lane] + be1[lane];
      float y1 = (x1 - mean) * rstd * g1[64 + lane] + be1[64 + lane];
      hV1[(size_t)tile * 128 + lane] = y0;
      hV1[(size_t)tile * 128 + 64 + lane] = y1;
      hV1b[(size_t)tile * 128 + lane] = f2b(y0);
      hV1b[(size_t)tile * 128 + 64 + lane] = f2b(y1);
    }
    __syncthreads();

    uint16_t* tp;
    tp = xEc; xEc = xEn; xEn = tp;
    tp = xGc; xGc = xGn; xGn = tp;
  }
#undef NLOAD48
#undef NWRITE48
}

// ---------------- K2: position-wise FFN + LN2 + mask_V ----------------
__global__ __launch_bounds__(256, 2) void k_ffn(
    const float* __restrict__ hV1, const uint16_t* __restrict__ hV1b,
    const float* __restrict__ maskV,
    const float* __restrict__ bdin, const float* __restrict__ bdout,
    const float* __restrict__ g2, const float* __restrict__ be2,
    const uint16_t* __restrict__ WdInT, const uint16_t* __restrict__ WdOutT,
    float* __restrict__ outV, uint16_t* __restrict__ hV2b) {
  __shared__ __align__(16) unsigned char lds[20992];
  uint16_t* xa = (uint16_t*)lds;             // [16][136]
  uint16_t* mf = (uint16_t*)(lds + 4352);    // [16][520]
  float* epi = (float*)(lds + 4352);         // [16][132] overlays mf (barrier-protected)

  const int tid = threadIdx.x;
  const int lane = tid & 63;
  const int w = tid >> 6;
  const int l15 = lane & 15;
  const int lg = lane >> 4;
  const int node0 = blockIdx.x * 16;

  {
    int row = tid >> 4, c = tid & 15;
    *(uint4*)(xa + row * 136 + (c << 3)) =
        *(const uint4*)(hV1b + (node0 + row) * 128 + (c << 3));
  }
  __syncthreads();

  f32x4 acc[8] = {};
  {
    const uint16_t* ar = xa + l15 * 136 + lg * 8;
#pragma unroll
    for (int ks = 0; ks < 4; ++ks) {
      bf16x8 a = *(const bf16x8*)(ar + ks * 32);
#pragma unroll
      for (int j = 0; j < 8; ++j) {
        bf16x8 bb = *(const bf16x8*)(WdInT + ((w * 8 + j) * 16 + l15) * 128 + ks * 32 + lg * 8);
        acc[j] = mfma16(a, bb, acc[j]);
      }
    }
  }
#pragma unroll
  for (int j = 0; j < 8; ++j) {
    int col = (w * 8 + j) * 16 + l15;
    float bs = bdin[col];
#pragma unroll
    for (int r = 0; r < 4; ++r) {
      int row = lg * 4 + r;
      mf[row * FFP + col] = f2b(gelu_f(acc[j][r] + bs));
    }
  }
  __syncthreads();

  f32x4 acc2[2] = {};
  {
    const uint16_t* mr = mf + l15 * FFP + lg * 8;
#pragma unroll 4
    for (int ks = 0; ks < 16; ++ks) {
      bf16x8 a = *(const bf16x8*)(mr + ks * 32);
#pragma unroll
      for (int t = 0; t < 2; ++t) {
        bf16x8 bb = *(const bf16x8*)(WdOutT + ((w * 2 + t) * 16 + l15) * 512 + ks * 32 + lg * 8);
        acc2[t] = mfma16(a, bb, acc2[t]);
      }
    }
  }
  __syncthreads();
#pragma unroll
  for (int t = 0; t < 2; ++t) {
    int col = (w * 2 + t) * 16 + l15;
    float bs = bdout[col];
#pragma unroll
    for (int r = 0; r < 4; ++r) {
      int row = lg * 4 + r;
      epi[row * EPIP + col] = acc2[t][r] + bs;
    }
  }
  __syncthreads();

#pragma unroll
  for (int rr = 0; rr < 4; ++rr) {
    int row = w * 4 + rr;
    int node = node0 + row;
    float x0 = epi[row * EPIP + lane] + hV1[node * 128 + lane];
    float x1 = epi[row * EPIP + 64 + lane] + hV1[node * 128 + 64 + lane];
    float s = x0 + x1, q = x0 * x0 + x1 * x1;
#pragma unroll
    for (int off = 1; off < 64; off <<= 1) {
      s += __shfl_xor(s, off);
      q += __shfl_xor(q, off);
    }
    float mean = s * (1.0f / 128.0f);
    float var = q * (1.0f / 128.0f) - mean * mean;
    float rstd = rsqrtf(var + 1e-5f);
    float mv = maskV[node];
    float y0 = mv * ((x0 - mean) * rstd * g2[lane] + be2[lane]);
    float y1 = mv * ((x1 - mean) * rstd * g2[64 + lane] + be2[64 + lane]);
    outV[node * 128 + lane] = y0;
    outV[node * 128 + 64 + lane] = y1;
    hV2b[node * 128 + lane] = f2b(y0);
    hV2b[node * 128 + 64 + lane] = f2b(y1);
  }
}

// ---------------- K3: edge MLP + residual + LN3 (M=32, pipelined 8 tiles) ----------------
// LDS: xE0 @0 | xE1 @8704 | xG0 @17408 | xG1 @26112 | mid @34816 |
//      part_s @43520 | part_q @44032 | mstd @44544 = 44800 B -> 3 blocks/CU
__global__ __launch_bounds__(256, 3) void k_edge(
    const float* __restrict__ hE, const int* __restrict__ eidx,
    const float* __restrict__ bias2, const float* __restrict__ bias3,
    const float* __restrict__ g3, const float* __restrict__ be3,
    const uint16_t* __restrict__ hV2b, const float* __restrict__ C2,
    const uint16_t* __restrict__ W1t, const uint16_t* __restrict__ W2t,
    const uint16_t* __restrict__ W3t,
    float* __restrict__ outE) {
  __shared__ __align__(16) unsigned char lds[44800];
  uint16_t* xE0 = (uint16_t*)lds;
  uint16_t* xE1 = (uint16_t*)(lds + 8704);
  uint16_t* xG0 = (uint16_t*)(lds + 17408);
  uint16_t* xG1 = (uint16_t*)(lds + 26112);
  uint16_t* mid = (uint16_t*)(lds + 34816);
  float* part_s = (float*)(lds + 43520);  // [32][4]
  float* part_q = (float*)(lds + 44032);  // [32][4]
  float* mstd = (float*)(lds + 44544);    // [32][2]

  const int tid = threadIdx.x;
  const int lane = tid & 63;
  const int w = tid >> 6;
  const int l15 = lane & 15;
  const int lg = lane >> 4;

  float4 fA0, fA1, fA2, fA3;
  uint4 gA0, gA1;

#define ELOAD32(TB)                                                                 \
  {                                                                                 \
    int row_ = tid >> 3, p_ = tid & 7;                                              \
    const float* sE_ = hE + (size_t)((TB) + row_) * 128 + p_ * 16;                  \
    fA0 = *(const float4*)sE_;       fA1 = *(const float4*)(sE_ + 4);               \
    fA2 = *(const float4*)(sE_ + 8); fA3 = *(const float4*)(sE_ + 12);              \
    int e_ = (TB) + row_;                                                           \
    int nb_ = ((e_ >= 98304) ? 2048 : 0) + eidx[e_];                                \
    const uint16_t* sG_ = hV2b + (size_t)nb_ * 128 + p_ * 16;                       \
    gA0 = *(const uint4*)sG_;  gA1 = *(const uint4*)(sG_ + 8);                      \
  }

#define EWRITE32(XE, XG)                                                            \
  {                                                                                 \
    int row_ = tid >> 3, p_ = tid & 7;                                              \
    uint4 v0_ = make_uint4(pk2f(fA0.x, fA0.y), pk2f(fA0.z, fA0.w),                  \
                           pk2f(fA1.x, fA1.y), pk2f(fA1.z, fA1.w));                 \
    uint4 v1_ = make_uint4(pk2f(fA2.x, fA2.y), pk2f(fA2.z, fA2.w),                  \
                           pk2f(fA3.x, fA3.y), pk2f(fA3.z, fA3.w));                 \
    *(uint4*)((XE) + row_ * MP + p_ * 16) = v0_;                                    \
    *(uint4*)((XE) + row_ * MP + p_ * 16 + 8) = v1_;                                \
    *(uint4*)((XG) + row_ * MP + p_ * 16) = gA0;                                    \
    *(uint4*)((XG) + row_ * MP + p_ * 16 + 8) = gA1;                                \
  }

  uint16_t *xEc = xE0, *xEn = xE1, *xGc = xG0, *xGn = xG1;

  ELOAD32(blockIdx.x * 32);
  EWRITE32(xEc, xGc);
  __syncthreads();

  for (int t = 0; t < 8; ++t) {
    const int tile = t * 768 + blockIdx.x;
    const int tbase = tile * 32;
    if (t < 7) ELOAD32((tile + 768) * 32);

    f32x4 acc1[2][2];
#pragma unroll
    for (int m = 0; m < 2; ++m)
#pragma unroll
      for (int r = 0; r < 4; ++r) {
        int row = m * 16 + lg * 4 + r;
        int nd = div48(tbase + row);
        acc1[m][0][r] = C2[(size_t)nd * 128 + w * 32 + l15];
        acc1[m][1][r] = C2[(size_t)nd * 128 + w * 32 + 16 + l15];
      }
    LAYER256S(W1t, xEc, xGc, acc1, 2);
    GSTORE0M(acc1, mid, 2);
    __syncthreads();

    f32x4 acc2[2][2] = {};
    LAYER128S(W2t, mid, acc2, 2);
    __syncthreads();               // all mid reads done before overwrite
    GSTOREM(acc2, bias2, mid, 2);
    __syncthreads();

    f32x4 acc3[2][2] = {};
    LAYER128S(W3t, mid, acc3, 2);
    if (t < 7) EWRITE32(xEn, xGn);

    const float bA = bias3[w * 32 + l15];
    const float bB = bias3[w * 32 + 16 + l15];

    // x = acc3 + bias + residual (hE read back from staged LDS tile, bf16)
    float xs0[2][4], xs1[2][4];
#pragma unroll
    for (int m = 0; m < 2; ++m)
#pragma unroll
      for (int r = 0; r < 4; ++r) {
        int row = m * 16 + lg * 4 + r;
        float r0 = b2f(xEc[row * MP + w * 32 + l15]);
        float r1 = b2f(xEc[row * MP + w * 32 + 16 + l15]);
        xs0[m][r] = acc3[m][0][r] + bA + r0;
        xs1[m][r] = acc3[m][1][r] + bB + r1;
        float s = xs0[m][r] + xs1[m][r];
        float q = xs0[m][r] * xs0[m][r] + xs1[m][r] * xs1[m][r];
        s += __shfl_xor(s, 1); q += __shfl_xor(q, 1);
        s += __shfl_xor(s, 2); q += __shfl_xor(q, 2);
        s += __shfl_xor(s, 4); q += __shfl_xor(q, 4);
        s += __shfl_xor(s, 8); q += __shfl_xor(q, 8);
        if (l15 == 0) { part_s[row * 4 + w] = s; part_q[row * 4 + w] = q; }
      }
    __syncthreads();

    if (tid < 32) {
      float s = part_s[tid * 4] + part_s[tid * 4 + 1] + part_s[tid * 4 + 2] + part_s[tid * 4 + 3];
      float q = part_q[tid * 4] + part_q[tid * 4 + 1] + part_q[tid * 4 + 2] + part_q[tid * 4 + 3];
      float mean = s * (1.0f / 128.0f);
      float var = q * (1.0f / 128.0f) - mean * mean;
      mstd[tid * 2] = mean;
      mstd[tid * 2 + 1] = rsqrtf(var + 1e-5f);
    }
    __syncthreads();

    const float gA = g3[w * 32 + l15], beA = be3[w * 32 + l15];
    const float gB = g3[w * 32 + 16 + l15], beB = be3[w * 32 + 16 + l15];
#pragma unroll
    for (int m = 0; m < 2; ++m)
#pragma unroll
      for (int r = 0; r < 4; ++r) {
        int row = m * 16 + lg * 4 + r;
        size_t e = (size_t)tbase + row;
        float mean = mstd[row * 2];
        float rstd = mstd[row * 2 + 1];
        outE[e * 128 + w * 32 + l15] = (xs0[m][r] - mean) * rstd * gA + beA;
        outE[e * 128 + w * 32 + 16 + l15] = (xs1[m][r] - mean) * rstd * gB + beB;
      }
    __syncthreads();

    uint16_t* tp;
    tp = xEc; xEc = xEn; xEn = tp;
    tp = xGc; xGc = xGn; xGn = tp;
  }
#undef ELOAD32
#undef EWRITE32
}

extern "C" void kernel_launch(void* const* d_in, const int* in_sizes, int n_in,
                              void* d_out, int out_size, void* d_ws, size_t ws_size,
                              hipStream_t stream) {
  const float* hV = (const float*)d_in[0];
  const float* hE = (const float*)d_in[1];
  const int* eidx = (const int*)d_in[2];
  const float* maskV = (const float*)d_in[3];
  const float* maskA = (const float*)d_in[4];
  const float* W1 = (const float*)d_in[5];   const float* b1 = (const float*)d_in[6];
  const float* W2 = (const float*)d_in[7];   const float* b2 = (const float*)d_in[8];
  const float* W3 = (const float*)d_in[9];   const float* b3 = (const float*)d_in[10];
  const float* WdIn = (const float*)d_in[11];  const float* bdin = (const float*)d_in[12];
  const float* WdOut = (const float*)d_in[13]; const float* bdout = (const float*)d_in[14];
  const float* W11 = (const float*)d_in[15]; const float* b11 = (const float*)d_in[16];
  const float* W12 = (const float*)d_in[17]; const float* b12 = (const float*)d_in[18];
  const float* W13 = (const float*)d_in[19]; const float* b13 = (const float*)d_in[20];
  const float* n1g = (const float*)d_in[21]; const float* n1b = (const float*)d_in[22];
  const float* n2g = (const float*)d_in[23]; const float* n2b = (const float*)d_in[24];
  const float* n3g = (const float*)d_in[25]; const float* n3b = (const float*)d_in[26];

  char* ws = (char*)d_ws;
  uint16_t* hVb    = (uint16_t*)(ws + 0);
  uint16_t* W1t    = (uint16_t*)(ws + 1048576);
  uint16_t* W2t    = (uint16_t*)(ws + 1146880);
  uint16_t* W3t    = (uint16_t*)(ws + 1179648);
  uint16_t* WdInT  = (uint16_t*)(ws + 1212416);
  uint16_t* WdOutT = (uint16_t*)(ws + 1343488);
  uint16_t* W11t   = (uint16_t*)(ws + 1474560);
  uint16_t* W12t   = (uint16_t*)(ws + 1572864);
  uint16_t* W13t   = (uint16_t*)(ws + 1605632);
  float*    hV1    = (float*)(ws + 1638400);
  uint16_t* hV1b   = (uint16_t*)(ws + 3735552);
  uint16_t* hV2b   = (uint16_t*)(ws + 4784128);
  float*    C1     = (float*)(ws + 5832704);
  float*    C2     = (float*)(ws + 7929856);

  float* outV = (float*)d_out;
  float* outE = (float*)d_out + 524288;

  k_prep<<<3200, 256, 0, stream>>>(hV, W1, W2, W3, WdIn, WdOut, W11, W12, W13,
                                   hVb, W1t, W2t, W3t, WdInT, WdOutT, W11t, W12t, W13t);
  k_vec<<<64, 256, 0, stream>>>(hVb, W1t, b1, C1);
  k_node<<<512, 256, 0, stream>>>(hV, hE, eidx, maskA, b2, b3, n1g, n1b,
                                  hVb, C1, W1t, W2t, W3t, hV1, hV1b);
  k_ffn<<<256, 256, 0, stream>>>(hV1, hV1b, maskV, bdin, bdout, n2g, n2b,
                                 WdInT, WdOutT, outV, hV2b);
  k_vec<<<64, 256, 0, stream>>>(hV2b, W11t, b11, C2);
  k_edge<<<768, 256, 0, stream>>>(hE, eidx, b12, b13, n3g, n3b,
                                  hV2b, C2, W11t, W12t, W13t, outE);
}

// Round 12
// 222.564 us; speedup vs baseline: 1.3024x; 1.3024x over previous
//
#include <hip/hip_runtime.h>
#include <hip/hip_bf16.h>
#include <stdint.h>

// Problem constants: B=2, N=2048, K=48, H=128, 3H=384, FF=512
// 2 nodes per block: 96 edge rows, 4 waves, wave w owns out-cols w*32..w*32+31.
// XCD-bijective block swizzle: each XCD gets a contiguous tile range (T1).
#define XP2 264     // x_tile pitch (bf16): 132 dwords (132%32=4 -> 2-way, free)
#define MP 136      // mid pitch (bf16): 68 dwords (68%32=4)
#define FFP 520     // ffn mid pitch
#define EPIP 132

typedef __attribute__((ext_vector_type(8))) short bf16x8;
typedef __attribute__((ext_vector_type(4))) float f32x4;

__device__ __forceinline__ f32x4 mfma16(bf16x8 a, bf16x8 b, f32x4 c) {
  return __builtin_amdgcn_mfma_f32_16x16x32_bf16(a, b, c, 0, 0, 0);
}

__device__ __forceinline__ uint16_t f2b(float f) {
  union { __hip_bfloat16 h; uint16_t u; } v;
  v.h = __float2bfloat16(f);
  return v.u;
}
__device__ __forceinline__ uint32_t pk2f(float a, float b) {
  union { __hip_bfloat162 h; uint32_t u; } v;
  v.h = __float22bfloat162_rn(make_float2(a, b));
  return v.u;
}
__device__ __forceinline__ float gelu_f(float x) {
  float u = __builtin_fmaf(x * x, 0.044715f, 1.0f);
  float e = __builtin_amdgcn_exp2f(-2.302585093f * x * u);
  return x * __builtin_amdgcn_rcpf(1.0f + e);
}

// ---------------- prep: bf16 h_V + transposed bf16 weights ----------------
__global__ __launch_bounds__(256) void k_prep(
    const float* __restrict__ hV,
    const float* __restrict__ W1, const float* __restrict__ W2, const float* __restrict__ W3,
    const float* __restrict__ WdIn, const float* __restrict__ WdOut,
    const float* __restrict__ W11, const float* __restrict__ W12, const float* __restrict__ W13,
    uint16_t* __restrict__ hVb,
    uint16_t* __restrict__ W1t, uint16_t* __restrict__ W2t, uint16_t* __restrict__ W3t,
    uint16_t* __restrict__ WdInT, uint16_t* __restrict__ WdOutT,
    uint16_t* __restrict__ W11t, uint16_t* __restrict__ W12t, uint16_t* __restrict__ W13t) {
  int i = blockIdx.x * 256 + threadIdx.x;
  if (i < 524288) { hVb[i] = f2b(hV[i]); return; }
  int j = i - 524288;
  if (j < 49152) { int n = j / 384, k = j - n * 384; W1t[j] = f2b(W1[k * 128 + n]); return; }
  j -= 49152;
  if (j < 16384) { int n = j >> 7, k = j & 127; W2t[j] = f2b(W2[k * 128 + n]); return; }
  j -= 16384;
  if (j < 16384) { int n = j >> 7, k = j & 127; W3t[j] = f2b(W3[k * 128 + n]); return; }
  j -= 16384;
  if (j < 65536) { int n = j >> 7, k = j & 127; WdInT[j] = f2b(WdIn[k * 512 + n]); return; }
  j -= 65536;
  if (j < 65536) { int n = j >> 9, k = j & 511; WdOutT[j] = f2b(WdOut[k * 128 + n]); return; }
  j -= 65536;
  if (j < 49152) { int n = j / 384, k = j - n * 384; W11t[j] = f2b(W11[k * 128 + n]); return; }
  j -= 49152;
  if (j < 16384) { int n = j >> 7, k = j & 127; W12t[j] = f2b(W12[k * 128 + n]); return; }
  j -= 16384;
  if (j < 16384) { int n = j >> 7, k = j & 127; W13t[j] = f2b(W13[k * 128 + n]); return; }
}

// ------- k_vec: C[i][n] = sum_{k<128} Xb[i][k]*Wt[n][k] + bias[n] -------
__global__ __launch_bounds__(256) void k_vec(
    const uint16_t* __restrict__ Xb, const uint16_t* __restrict__ Wt,
    const float* __restrict__ bias, float* __restrict__ C) {
  const int tid = threadIdx.x;
  const int lane = tid & 63, w = tid >> 6, l15 = lane & 15, lg = lane >> 4;
  const int row0 = blockIdx.x * 64 + w * 16;
  f32x4 acc[8] = {};
#pragma unroll
  for (int ks = 0; ks < 4; ++ks) {
    bf16x8 a = *(const bf16x8*)(Xb + (row0 + l15) * 128 + ks * 32 + lg * 8);
#pragma unroll
    for (int j = 0; j < 8; ++j) {
      bf16x8 bb = *(const bf16x8*)(Wt + (j * 16 + l15) * 384 + ks * 32 + lg * 8);
      acc[j] = mfma16(a, bb, acc[j]);
    }
  }
#pragma unroll
  for (int j = 0; j < 8; ++j) {
    float bs = bias[j * 16 + l15];
#pragma unroll
    for (int r = 0; r < 4; ++r)
      C[(row0 + lg * 4 + r) * 128 + j * 16 + l15] = acc[j][r] + bs;
  }
}

// ===== 96-row block-staged MLP macros =====
#define BUILD_XT96(GSRC)                                                            \
  do {                                                                              \
    for (int idx = tid; idx < 96 * 32; idx += 256) {                                \
      int k_ = idx >> 5;                                                            \
      int c_ = idx & 31;                                                            \
      uint4 v_;                                                                     \
      if (c_ < 16) {                                                                \
        const float* s_ = hE + (size_t)(base + k_) * 128 + (c_ << 3);               \
        float4 f0_ = *(const float4*)s_;                                            \
        float4 f1_ = *(const float4*)(s_ + 4);                                      \
        v_ = make_uint4(pk2f(f0_.x, f0_.y), pk2f(f0_.z, f0_.w),                     \
                        pk2f(f1_.x, f1_.y), pk2f(f1_.z, f1_.w));                    \
      } else {                                                                      \
        v_ = *(const uint4*)((GSRC) + (size_t)nbr[k_] * 128 + ((c_ - 16) << 3));    \
      }                                                                             \
      *(uint4*)(xt + k_ * XP2 + (c_ << 3)) = v_;                                    \
    }                                                                               \
  } while (0)

#define PRELOAD_W384(WT, WF)                                                        \
  do {                                                                              \
    const uint16_t* p0_ = (WT) + (w * 32 + l15) * 384 + 128 + lg * 8;               \
    const uint16_t* p1_ = p0_ + 16 * 384;                                           \
    _Pragma("unroll") for (int ks = 0; ks < 8; ++ks) {                              \
      WF[ks] = *(const bf16x8*)(p0_ + ks * 32);                                     \
      WF[8 + ks] = *(const bf16x8*)(p1_ + ks * 32);                                 \
    }                                                                               \
  } while (0)

#define PRELOAD_W128(WT, WF)                                                        \
  do {                                                                              \
    const uint16_t* p0_ = (WT) + (w * 32 + l15) * 128 + lg * 8;                     \
    const uint16_t* p1_ = p0_ + 16 * 128;                                           \
    _Pragma("unroll") for (int ks = 0; ks < 4; ++ks) {                              \
      WF[ks] = *(const bf16x8*)(p0_ + ks * 32);                                     \
      WF[4 + ks] = *(const bf16x8*)(p1_ + ks * 32);                                 \
    }                                                                               \
  } while (0)

#define LAYER256R6(WF, ACC)                                                         \
  do {                                                                              \
    _Pragma("unroll") for (int ks = 0; ks < 8; ++ks)                                \
    _Pragma("unroll") for (int m = 0; m < 6; ++m) {                                 \
      bf16x8 a_ = *(const bf16x8*)(xt + (m * 16 + l15) * XP2 + ks * 32 + lg * 8);   \
      ACC[m][0] = mfma16(a_, WF[ks], ACC[m][0]);                                    \
      ACC[m][1] = mfma16(a_, WF[8 + ks], ACC[m][1]);                                \
    }                                                                               \
  } while (0)

#define LAYER128R6(WF, ASRC, ACC)                                                   \
  do {                                                                              \
    _Pragma("unroll") for (int ks = 0; ks < 4; ++ks)                                \
    _Pragma("unroll") for (int m = 0; m < 6; ++m) {                                 \
      bf16x8 a_ = *(const bf16x8*)((ASRC) + (m * 16 + l15) * MP + ks * 32 + lg * 8);\
      ACC[m][0] = mfma16(a_, WF[ks], ACC[m][0]);                                    \
      ACC[m][1] = mfma16(a_, WF[4 + ks], ACC[m][1]);                                \
    }                                                                               \
  } while (0)

#define GSTORE6(ACC, BIAS, DST)                                                     \
  do {                                                                              \
    float bA_ = (BIAS)[w * 32 + l15];                                               \
    float bB_ = (BIAS)[w * 32 + 16 + l15];                                          \
    _Pragma("unroll") for (int m = 0; m < 6; ++m)                                   \
    _Pragma("unroll") for (int r = 0; r < 4; ++r) {                                 \
      int row_ = m * 16 + lg * 4 + r;                                               \
      (DST)[row_ * MP + w * 32 + l15] = f2b(gelu_f(ACC[m][0][r] + bA_));            \
      (DST)[row_ * MP + w * 32 + 16 + l15] = f2b(gelu_f(ACC[m][1][r] + bB_));       \
    }                                                                               \
  } while (0)

#define GSTORE06(ACC, DST)                                                          \
  do {                                                                              \
    _Pragma("unroll") for (int m = 0; m < 6; ++m)                                   \
    _Pragma("unroll") for (int r = 0; r < 4; ++r) {                                 \
      int row_ = m * 16 + lg * 4 + r;                                               \
      (DST)[row_ * MP + w * 32 + l15] = f2b(gelu_f(ACC[m][0][r]));                  \
      (DST)[row_ * MP + w * 32 + 16 + l15] = f2b(gelu_f(ACC[m][1][r]));             \
    }                                                                               \
  } while (0)

#define ACC_INIT6(ACC, CV)                                                          \
  do {                                                                              \
    float c0a_ = (CV)[(size_t)nd0 * 128 + w * 32 + l15];                            \
    float c1a_ = (CV)[(size_t)nd0 * 128 + w * 32 + 16 + l15];                       \
    float c0b_ = (CV)[(size_t)(nd0 + 1) * 128 + w * 32 + l15];                      \
    float c1b_ = (CV)[(size_t)(nd0 + 1) * 128 + w * 32 + 16 + l15];                 \
    _Pragma("unroll") for (int m = 0; m < 6; ++m) {                                 \
      float a_ = (m < 3) ? c0a_ : c0b_;                                             \
      float b_ = (m < 3) ? c1a_ : c1b_;                                             \
      ACC[m][0] = (f32x4){a_, a_, a_, a_};                                          \
      ACC[m][1] = (f32x4){b_, b_, b_, b_};                                          \
    }                                                                               \
  } while (0)

// ---------------- K1: node message MLP + masked sum + LN1 (2 nodes/block) ----------------
__global__ __launch_bounds__(256, 3) void k_node(
    const float* __restrict__ hV, const float* __restrict__ hE,
    const int* __restrict__ eidx, const float* __restrict__ maskA,
    const float* __restrict__ bias2, const float* __restrict__ bias3,
    const float* __restrict__ g1, const float* __restrict__ be1,
    const uint16_t* __restrict__ hVb, const float* __restrict__ C1,
    const uint16_t* __restrict__ W1t, const uint16_t* __restrict__ W2t,
    const uint16_t* __restrict__ W3t,
    float* __restrict__ hV1, uint16_t* __restrict__ hV1b) {
  __shared__ __align__(16) unsigned char lds[52608];
  uint16_t* xt = (uint16_t*)lds;
  uint16_t* midA = (uint16_t*)lds;             // overlays xt after post-L1 barrier
  uint16_t* midB = (uint16_t*)(lds + 26112);
  int* nbr = (int*)(lds + 52224);
  float* dh = (float*)lds;                     // [2][128], overlays dead midA

  const int tid = threadIdx.x;
  const int lane = tid & 63;
  const int w = tid >> 6;
  const int l15 = lane & 15;
  const int lg = lane >> 4;
  // bijective XCD swizzle: 2048 blocks, 8 XCDs -> contiguous 256-block chunks
  const int bid = ((blockIdx.x & 7) << 8) | (blockIdx.x >> 3);
  const int nd0 = bid * 2;
  const int base = bid * 96;                   // first edge row

  bf16x8 w1f[16];
  PRELOAD_W384(W1t, w1f);

  if (tid < 96) {
    int e = base + tid;
    nbr[tid] = ((e >= 98304) ? 2048 : 0) + eidx[e];
  }
  __syncthreads();

  BUILD_XT96(hVb);
  __syncthreads();

  f32x4 acc1[6][2];
  ACC_INIT6(acc1, C1);
  LAYER256R6(w1f, acc1);
  bf16x8 w2f[8];
  PRELOAD_W128(W2t, w2f);
  __syncthreads();               // all xt reads done; midA may overlay
  GSTORE06(acc1, midA);
  __syncthreads();

  f32x4 acc2[6][2] = {};
  LAYER128R6(w2f, midA, acc2);
  bf16x8 w3f[8];
  PRELOAD_W128(W3t, w3f);
  GSTORE6(acc2, bias2, midB);
  __syncthreads();               // midA reads done (dh overlay safe after this)

  f32x4 acc3[6][2] = {};
  LAYER128R6(w3f, midB, acc3);

  // masked column sums per node over its 48 rows
  {
    float bA = bias3[w * 32 + l15];
    float bB = bias3[w * 32 + 16 + l15];
    float s0a = 0.f, s1a = 0.f, s0b = 0.f, s1b = 0.f;
#pragma unroll
    for (int m = 0; m < 6; ++m)
#pragma unroll
      for (int r = 0; r < 4; ++r) {
        int row = m * 16 + lg * 4 + r;
        float mk = maskA[base + row];
        float v0 = (acc3[m][0][r] + bA) * mk;
        float v1 = (acc3[m][1][r] + bB) * mk;
        if (m < 3) { s0a += v0; s1a += v1; } else { s0b += v0; s1b += v1; }
      }
    s0a += __shfl_xor(s0a, 16); s0a += __shfl_xor(s0a, 32);
    s1a += __shfl_xor(s1a, 16); s1a += __shfl_xor(s1a, 32);
    s0b += __shfl_xor(s0b, 16); s0b += __shfl_xor(s0b, 32);
    s1b += __shfl_xor(s1b, 16); s1b += __shfl_xor(s1b, 32);
    if (lg == 0) {
      dh[w * 32 + l15] = s0a;        dh[w * 32 + 16 + l15] = s1a;
      dh[128 + w * 32 + l15] = s0b;  dh[128 + w * 32 + 16 + l15] = s1b;
    }
  }
  __syncthreads();

  if (w < 2) {
    int node = nd0 + w;
    const float inv = 1.0f / 30.0f;
    float x0 = hV[(size_t)node * 128 + lane] + dh[w * 128 + lane] * inv;
    float x1 = hV[(size_t)node * 128 + 64 + lane] + dh[w * 128 + 64 + lane] * inv;
    float s = x0 + x1, q = x0 * x0 + x1 * x1;
#pragma unroll
    for (int off = 1; off < 64; off <<= 1) {
      s += __shfl_xor(s, off);
      q += __shfl_xor(q, off);
    }
    float mean = s * (1.0f / 128.0f);
    float var = q * (1.0f / 128.0f) - mean * mean;
    float rstd = rsqrtf(var + 1e-5f);
    float y0 = (x0 - mean) * rstd * g1[lane] + be1[lane];
    float y1 = (x1 - mean) * rstd * g1[64 + lane] + be1[64 + lane];
    hV1[(size_t)node * 128 + lane] = y0;
    hV1[(size_t)node * 128 + 64 + lane] = y1;
    hV1b[(size_t)node * 128 + lane] = f2b(y0);
    hV1b[(size_t)node * 128 + 64 + lane] = f2b(y1);
  }
}

// ---------------- K2: position-wise FFN + LN2 + mask_V ----------------
__global__ __launch_bounds__(256, 2) void k_ffn(
    const float* __restrict__ hV1, const uint16_t* __restrict__ hV1b,
    const float* __restrict__ maskV,
    const float* __restrict__ bdin, const float* __restrict__ bdout,
    const float* __restrict__ g2, const float* __restrict__ be2,
    const uint16_t* __restrict__ WdInT, const uint16_t* __restrict__ WdOutT,
    float* __restrict__ outV, uint16_t* __restrict__ hV2b) {
  __shared__ __align__(16) unsigned char lds[20992];
  uint16_t* xa = (uint16_t*)lds;             // [16][136]
  uint16_t* mf = (uint16_t*)(lds + 4352);    // [16][520]
  float* epi = (float*)(lds + 4352);         // [16][132] overlays mf (barrier-protected)

  const int tid = threadIdx.x;
  const int lane = tid & 63;
  const int w = tid >> 6;
  const int l15 = lane & 15;
  const int lg = lane >> 4;
  // bijective XCD swizzle: 256 blocks -> 32-block chunks per XCD
  const int bid = ((blockIdx.x & 7) << 5) | (blockIdx.x >> 3);
  const int node0 = bid * 16;

  {
    int row = tid >> 4, c = tid & 15;
    *(uint4*)(xa + row * 136 + (c << 3)) =
        *(const uint4*)(hV1b + (node0 + row) * 128 + (c << 3));
  }
  __syncthreads();

  f32x4 acc[8] = {};
  {
    const uint16_t* ar = xa + l15 * 136 + lg * 8;
#pragma unroll
    for (int ks = 0; ks < 4; ++ks) {
      bf16x8 a = *(const bf16x8*)(ar + ks * 32);
#pragma unroll
      for (int j = 0; j < 8; ++j) {
        bf16x8 bb = *(const bf16x8*)(WdInT + ((w * 8 + j) * 16 + l15) * 128 + ks * 32 + lg * 8);
        acc[j] = mfma16(a, bb, acc[j]);
      }
    }
  }
#pragma unroll
  for (int j = 0; j < 8; ++j) {
    int col = (w * 8 + j) * 16 + l15;
    float bs = bdin[col];
#pragma unroll
    for (int r = 0; r < 4; ++r) {
      int row = lg * 4 + r;
      mf[row * FFP + col] = f2b(gelu_f(acc[j][r] + bs));
    }
  }
  __syncthreads();

  f32x4 acc2[2] = {};
  {
    const uint16_t* mr = mf + l15 * FFP + lg * 8;
#pragma unroll 4
    for (int ks = 0; ks < 16; ++ks) {
      bf16x8 a = *(const bf16x8*)(mr + ks * 32);
#pragma unroll
      for (int t = 0; t < 2; ++t) {
        bf16x8 bb = *(const bf16x8*)(WdOutT + ((w * 2 + t) * 16 + l15) * 512 + ks * 32 + lg * 8);
        acc2[t] = mfma16(a, bb, acc2[t]);
      }
    }
  }
  __syncthreads();
#pragma unroll
  for (int t = 0; t < 2; ++t) {
    int col = (w * 2 + t) * 16 + l15;
    float bs = bdout[col];
#pragma unroll
    for (int r = 0; r < 4; ++r) {
      int row = lg * 4 + r;
      epi[row * EPIP + col] = acc2[t][r] + bs;
    }
  }
  __syncthreads();

#pragma unroll
  for (int rr = 0; rr < 4; ++rr) {
    int row = w * 4 + rr;
    int node = node0 + row;
    float x0 = epi[row * EPIP + lane] + hV1[node * 128 + lane];
    float x1 = epi[row * EPIP + 64 + lane] + hV1[node * 128 + 64 + lane];
    float s = x0 + x1, q = x0 * x0 + x1 * x1;
#pragma unroll
    for (int off = 1; off < 64; off <<= 1) {
      s += __shfl_xor(s, off);
      q += __shfl_xor(q, off);
    }
    float mean = s * (1.0f / 128.0f);
    float var = q * (1.0f / 128.0f) - mean * mean;
    float rstd = rsqrtf(var + 1e-5f);
    float mv = maskV[node];
    float y0 = mv * ((x0 - mean) * rstd * g2[lane] + be2[lane]);
    float y1 = mv * ((x1 - mean) * rstd * g2[64 + lane] + be2[64 + lane]);
    outV[node * 128 + lane] = y0;
    outV[node * 128 + 64 + lane] = y1;
    hV2b[node * 128 + lane] = f2b(y0);
    hV2b[node * 128 + 64 + lane] = f2b(y1);
  }
}

// ---------------- K3: edge MLP + residual + LN3 (2 nodes/block) ----------------
__global__ __launch_bounds__(256, 3) void k_edge(
    const float* __restrict__ hE, const int* __restrict__ eidx,
    const float* __restrict__ bias2, const float* __restrict__ bias3,
    const float* __restrict__ g3, const float* __restrict__ be3,
    const uint16_t* __restrict__ hV2b, const float* __restrict__ C2,
    const uint16_t* __restrict__ W1t, const uint16_t* __restrict__ W2t,
    const uint16_t* __restrict__ W3t,
    float* __restrict__ outE) {
  __shared__ __align__(16) unsigned char lds[52608];
  uint16_t* xt = (uint16_t*)lds;
  uint16_t* midA = (uint16_t*)lds;
  uint16_t* midB = (uint16_t*)(lds + 26112);
  int* nbr = (int*)(lds + 52224);
  float* part_s = (float*)lds;            // [96][4] overlays dead midA
  float* part_q = (float*)(lds + 1536);   // [96][4]
  float* mstd = (float*)(lds + 3072);     // [96][2] (mean, rstd)

  const int tid = threadIdx.x;
  const int lane = tid & 63;
  const int w = tid >> 6;
  const int l15 = lane & 15;
  const int lg = lane >> 4;
  // bijective XCD swizzle: 2048 blocks -> contiguous 256-block chunks per XCD
  const int bid = ((blockIdx.x & 7) << 8) | (blockIdx.x >> 3);
  const int nd0 = bid * 2;
  const int base = bid * 96;

  bf16x8 w1f[16];
  PRELOAD_W384(W1t, w1f);

  if (tid < 96) {
    int e = base + tid;
    nbr[tid] = ((e >= 98304) ? 2048 : 0) + eidx[e];
  }
  __syncthreads();

  BUILD_XT96(hV2b);
  __syncthreads();

  f32x4 acc1[6][2];
  ACC_INIT6(acc1, C2);
  LAYER256R6(w1f, acc1);
  bf16x8 w2f[8];
  PRELOAD_W128(W2t, w2f);
  __syncthreads();               // all xt reads done; midA may overlay
  GSTORE06(acc1, midA);
  __syncthreads();

  f32x4 acc2[6][2] = {};
  LAYER128R6(w2f, midA, acc2);
  bf16x8 w3f[8];
  PRELOAD_W128(W3t, w3f);
  GSTORE6(acc2, bias2, midB);
  __syncthreads();               // midA reads done (partials overlay safe)

  f32x4 acc3[6][2] = {};
  LAYER128R6(w3f, midB, acc3);

  const float bA = bias3[w * 32 + l15];
  const float bB = bias3[w * 32 + 16 + l15];

  // x = acc3 + bias + hE residual, cached in VGPRs for both LN passes
  float xs0[6][4], xs1[6][4];
#pragma unroll
  for (int m = 0; m < 6; ++m)
#pragma unroll
    for (int r = 0; r < 4; ++r) {
      int row = m * 16 + lg * 4 + r;
      size_t e = (size_t)base + row;
      xs0[m][r] = acc3[m][0][r] + bA + hE[e * 128 + w * 32 + l15];
      xs1[m][r] = acc3[m][1][r] + bB + hE[e * 128 + w * 32 + 16 + l15];
      float s = xs0[m][r] + xs1[m][r];
      float q = xs0[m][r] * xs0[m][r] + xs1[m][r] * xs1[m][r];
      s += __shfl_xor(s, 1); q += __shfl_xor(q, 1);
      s += __shfl_xor(s, 2); q += __shfl_xor(q, 2);
      s += __shfl_xor(s, 4); q += __shfl_xor(q, 4);
      s += __shfl_xor(s, 8); q += __shfl_xor(q, 8);
      if (l15 == 0) { part_s[row * 4 + w] = s; part_q[row * 4 + w] = q; }
    }
  __syncthreads();

  if (tid < 96) {
    float s = part_s[tid * 4] + part_s[tid * 4 + 1] + part_s[tid * 4 + 2] + part_s[tid * 4 + 3];
    float q = part_q[tid * 4] + part_q[tid * 4 + 1] + part_q[tid * 4 + 2] + part_q[tid * 4 + 3];
    float mean = s * (1.0f / 128.0f);
    float var = q * (1.0f / 128.0f) - mean * mean;
    mstd[tid * 2] = mean;
    mstd[tid * 2 + 1] = rsqrtf(var + 1e-5f);
  }
  __syncthreads();

  const float gA = g3[w * 32 + l15], beA = be3[w * 32 + l15];
  const float gB = g3[w * 32 + 16 + l15], beB = be3[w * 32 + 16 + l15];
#pragma unroll
  for (int m = 0; m < 6; ++m)
#pragma unroll
    for (int r = 0; r < 4; ++r) {
      int row = m * 16 + lg * 4 + r;
      size_t e = (size_t)base + row;
      float mean = mstd[row * 2];
      float rstd = mstd[row * 2 + 1];
      outE[e * 128 + w * 32 + l15] = (xs0[m][r] - mean) * rstd * gA + beA;
      outE[e * 128 + w * 32 + 16 + l15] = (xs1[m][r] - mean) * rstd * gB + beB;
    }
}

extern "C" void kernel_launch(void* const* d_in, const int* in_sizes, int n_in,
                              void* d_out, int out_size, void* d_ws, size_t ws_size,
                              hipStream_t stream) {
  const float* hV = (const float*)d_in[0];
  const float* hE = (const float*)d_in[1];
  const int* eidx = (const int*)d_in[2];
  const float* maskV = (const float*)d_in[3];
  const float* maskA = (const float*)d_in[4];
  const float* W1 = (const float*)d_in[5];   const float* b1 = (const float*)d_in[6];
  const float* W2 = (const float*)d_in[7];   const float* b2 = (const float*)d_in[8];
  const float* W3 = (const float*)d_in[9];   const float* b3 = (const float*)d_in[10];
  const float* WdIn = (const float*)d_in[11];  const float* bdin = (const float*)d_in[12];
  const float* WdOut = (const float*)d_in[13]; const float* bdout = (const float*)d_in[14];
  const float* W11 = (const float*)d_in[15]; const float* b11 = (const float*)d_in[16];
  const float* W12 = (const float*)d_in[17]; const float* b12 = (const float*)d_in[18];
  const float* W13 = (const float*)d_in[19]; const float* b13 = (const float*)d_in[20];
  const float* n1g = (const float*)d_in[21]; const float* n1b = (const float*)d_in[22];
  const float* n2g = (const float*)d_in[23]; const float* n2b = (const float*)d_in[24];
  const float* n3g = (const float*)d_in[25]; const float* n3b = (const float*)d_in[26];

  char* ws = (char*)d_ws;
  uint16_t* hVb    = (uint16_t*)(ws + 0);
  uint16_t* W1t    = (uint16_t*)(ws + 1048576);
  uint16_t* W2t    = (uint16_t*)(ws + 1146880);
  uint16_t* W3t    = (uint16_t*)(ws + 1179648);
  uint16_t* WdInT  = (uint16_t*)(ws + 1212416);
  uint16_t* WdOutT = (uint16_t*)(ws + 1343488);
  uint16_t* W11t   = (uint16_t*)(ws + 1474560);
  uint16_t* W12t   = (uint16_t*)(ws + 1572864);
  uint16_t* W13t   = (uint16_t*)(ws + 1605632);
  float*    hV1    = (float*)(ws + 1638400);
  uint16_t* hV1b   = (uint16_t*)(ws + 3735552);
  uint16_t* hV2b   = (uint16_t*)(ws + 4784128);
  float*    C1     = (float*)(ws + 5832704);
  float*    C2     = (float*)(ws + 7929856);

  float* outV = (float*)d_out;
  float* outE = (float*)d_out + 524288;

  k_prep<<<3200, 256, 0, stream>>>(hV, W1, W2, W3, WdIn, WdOut, W11, W12, W13,
                                   hVb, W1t, W2t, W3t, WdInT, WdOutT, W11t, W12t, W13t);
  k_vec<<<64, 256, 0, stream>>>(hVb, W1t, b1, C1);
  k_node<<<2048, 256, 0, stream>>>(hV, hE, eidx, maskA, b2, b3, n1g, n1b,
                                   hVb, C1, W1t, W2t, W3t, hV1, hV1b);
  k_ffn<<<256, 256, 0, stream>>>(hV1, hV1b, maskV, bdin, bdout, n2g, n2b,
                                 WdInT, WdOutT, outV, hV2b);
  k_vec<<<64, 256, 0, stream>>>(hV2b, W11t, b11, C2);
  k_edge<<<2048, 256, 0, stream>>>(hE, eidx, b12, b13, n3g, n3b,
                                   hV2b, C2, W11t, W12t, W13t, outE);
}

// Round 15
// 209.336 us; speedup vs baseline: 1.3847x; 1.0632x over previous
//
#include <hip/hip_runtime.h>
#include <hip/hip_bf16.h>
#include <stdint.h>

// Problem constants: B=2, N=2048, K=48, H=128, 3H=384, FF=512
// 2 nodes per block: 96 edge rows, 4 waves, wave w owns out-cols w*32..w*32+31.
#define XP2 264     // k_node x_tile pitch (bf16)
#define MP 136      // split-tile / mid pitch (bf16): 68 dwords (68%32=4)
#define FFP 520     // ffn mid pitch
#define EPIP 132

typedef __attribute__((ext_vector_type(8))) short bf16x8;
typedef __attribute__((ext_vector_type(4))) float f32x4;

__device__ __forceinline__ f32x4 mfma16(bf16x8 a, bf16x8 b, f32x4 c) {
  return __builtin_amdgcn_mfma_f32_16x16x32_bf16(a, b, c, 0, 0, 0);
}

__device__ __forceinline__ uint16_t f2b(float f) {
  union { __hip_bfloat16 h; uint16_t u; } v;
  v.h = __float2bfloat16(f);
  return v.u;
}
__device__ __forceinline__ float b2f(uint16_t h) {
  union { uint32_t u; float f; } v; v.u = ((uint32_t)h) << 16;
  return v.f;
}
__device__ __forceinline__ uint32_t pk2f(float a, float b) {
  union { __hip_bfloat162 h; uint32_t u; } v;
  v.h = __float22bfloat162_rn(make_float2(a, b));
  return v.u;
}
__device__ __forceinline__ float gelu_f(float x) {
  float u = __builtin_fmaf(x * x, 0.044715f, 1.0f);
  float e = __builtin_amdgcn_exp2f(-2.302585093f * x * u);
  return x * __builtin_amdgcn_rcpf(1.0f + e);
}

// ---------------- prep: bf16 h_V + transposed bf16 weights ----------------
__global__ __launch_bounds__(256) void k_prep(
    const float* __restrict__ hV,
    const float* __restrict__ W1, const float* __restrict__ W2, const float* __restrict__ W3,
    const float* __restrict__ WdIn, const float* __restrict__ WdOut,
    const float* __restrict__ W11, const float* __restrict__ W12, const float* __restrict__ W13,
    uint16_t* __restrict__ hVb,
    uint16_t* __restrict__ W1t, uint16_t* __restrict__ W2t, uint16_t* __restrict__ W3t,
    uint16_t* __restrict__ WdInT, uint16_t* __restrict__ WdOutT,
    uint16_t* __restrict__ W11t, uint16_t* __restrict__ W12t, uint16_t* __restrict__ W13t) {
  int i = blockIdx.x * 256 + threadIdx.x;
  if (i < 524288) { hVb[i] = f2b(hV[i]); return; }
  int j = i - 524288;
  if (j < 49152) { int n = j / 384, k = j - n * 384; W1t[j] = f2b(W1[k * 128 + n]); return; }
  j -= 49152;
  if (j < 16384) { int n = j >> 7, k = j & 127; W2t[j] = f2b(W2[k * 128 + n]); return; }
  j -= 16384;
  if (j < 16384) { int n = j >> 7, k = j & 127; W3t[j] = f2b(W3[k * 128 + n]); return; }
  j -= 16384;
  if (j < 65536) { int n = j >> 7, k = j & 127; WdInT[j] = f2b(WdIn[k * 512 + n]); return; }
  j -= 65536;
  if (j < 65536) { int n = j >> 9, k = j & 511; WdOutT[j] = f2b(WdOut[k * 128 + n]); return; }
  j -= 65536;
  if (j < 49152) { int n = j / 384, k = j - n * 384; W11t[j] = f2b(W11[k * 128 + n]); return; }
  j -= 49152;
  if (j < 16384) { int n = j >> 7, k = j & 127; W12t[j] = f2b(W12[k * 128 + n]); return; }
  j -= 16384;
  if (j < 16384) { int n = j >> 7, k = j & 127; W13t[j] = f2b(W13[k * 128 + n]); return; }
}

// ------- k_vec: C[i][n] = sum_{k<128} Xb[i][k]*Wt[n][k] + bias[n] -------
__global__ __launch_bounds__(256) void k_vec(
    const uint16_t* __restrict__ Xb, const uint16_t* __restrict__ Wt,
    const float* __restrict__ bias, float* __restrict__ C) {
  const int tid = threadIdx.x;
  const int lane = tid & 63, w = tid >> 6, l15 = lane & 15, lg = lane >> 4;
  const int row0 = blockIdx.x * 64 + w * 16;
  f32x4 acc[8] = {};
#pragma unroll
  for (int ks = 0; ks < 4; ++ks) {
    bf16x8 a = *(const bf16x8*)(Xb + (row0 + l15) * 128 + ks * 32 + lg * 8);
#pragma unroll
    for (int j = 0; j < 8; ++j) {
      bf16x8 bb = *(const bf16x8*)(Wt + (j * 16 + l15) * 384 + ks * 32 + lg * 8);
      acc[j] = mfma16(a, bb, acc[j]);
    }
  }
#pragma unroll
  for (int j = 0; j < 8; ++j) {
    float bs = bias[j * 16 + l15];
#pragma unroll
    for (int r = 0; r < 4; ++r)
      C[(row0 + lg * 4 + r) * 128 + j * 16 + l15] = acc[j][r] + bs;
  }
}

// ===== 96-row block-staged MLP macros =====
#define BUILD_XT96(GSRC)                                                            \
  do {                                                                              \
    for (int idx = tid; idx < 96 * 32; idx += 256) {                                \
      int k_ = idx >> 5;                                                            \
      int c_ = idx & 31;                                                            \
      uint4 v_;                                                                     \
      if (c_ < 16) {                                                                \
        const float* s_ = hE + (size_t)(base + k_) * 128 + (c_ << 3);               \
        float4 f0_ = *(const float4*)s_;                                            \
        float4 f1_ = *(const float4*)(s_ + 4);                                      \
        v_ = make_uint4(pk2f(f0_.x, f0_.y), pk2f(f0_.z, f0_.w),                     \
                        pk2f(f1_.x, f1_.y), pk2f(f1_.z, f1_.w));                    \
      } else {                                                                      \
        v_ = *(const uint4*)((GSRC) + (size_t)nbr[k_] * 128 + ((c_ - 16) << 3));    \
      }                                                                             \
      *(uint4*)(xt + k_ * XP2 + (c_ << 3)) = v_;                                    \
    }                                                                               \
  } while (0)

// split-destination staging: hE half -> xE [96][MP], gather half -> xG [96][MP]
#define BUILD_XT96S(GSRC)                                                           \
  do {                                                                              \
    for (int idx = tid; idx < 96 * 32; idx += 256) {                                \
      int k_ = idx >> 5;                                                            \
      int c_ = idx & 31;                                                            \
      if (c_ < 16) {                                                                \
        const float* s_ = hE + (size_t)(base + k_) * 128 + (c_ << 3);               \
        float4 f0_ = *(const float4*)s_;                                            \
        float4 f1_ = *(const float4*)(s_ + 4);                                      \
        uint4 v_ = make_uint4(pk2f(f0_.x, f0_.y), pk2f(f0_.z, f0_.w),               \
                              pk2f(f1_.x, f1_.y), pk2f(f1_.z, f1_.w));              \
        *(uint4*)(xE + k_ * MP + (c_ << 3)) = v_;                                   \
      } else {                                                                      \
        uint4 v_ = *(const uint4*)((GSRC) + (size_t)nbr[k_] * 128 +                 \
                                   ((c_ - 16) << 3));                               \
        *(uint4*)(xG + k_ * MP + ((c_ - 16) << 3)) = v_;                            \
      }                                                                             \
    }                                                                               \
  } while (0)

#define PRELOAD_W384(WT, WF)                                                        \
  do {                                                                              \
    const uint16_t* p0_ = (WT) + (w * 32 + l15) * 384 + 128 + lg * 8;               \
    const uint16_t* p1_ = p0_ + 16 * 384;                                           \
    _Pragma("unroll") for (int ks = 0; ks < 8; ++ks) {                              \
      WF[ks] = *(const bf16x8*)(p0_ + ks * 32);                                     \
      WF[8 + ks] = *(const bf16x8*)(p1_ + ks * 32);                                 \
    }                                                                               \
  } while (0)

#define PRELOAD_W128(WT, WF)                                                        \
  do {                                                                              \
    const uint16_t* p0_ = (WT) + (w * 32 + l15) * 128 + lg * 8;                     \
    const uint16_t* p1_ = p0_ + 16 * 128;                                           \
    _Pragma("unroll") for (int ks = 0; ks < 4; ++ks) {                              \
      WF[ks] = *(const bf16x8*)(p0_ + ks * 32);                                     \
      WF[4 + ks] = *(const bf16x8*)(p1_ + ks * 32);                                 \
    }                                                                               \
  } while (0)

#define LAYER256R6(WF, ACC)                                                         \
  do {                                                                              \
    _Pragma("unroll") for (int ks = 0; ks < 8; ++ks)                                \
    _Pragma("unroll") for (int m = 0; m < 6; ++m) {                                 \
      bf16x8 a_ = *(const bf16x8*)(xt + (m * 16 + l15) * XP2 + ks * 32 + lg * 8);   \
      ACC[m][0] = mfma16(a_, WF[ks], ACC[m][0]);                                    \
      ACC[m][1] = mfma16(a_, WF[8 + ks], ACC[m][1]);                                \
    }                                                                               \
  } while (0)

// split-source layer-1: ks 0..3 from xE (hE cols 128..255), ks 4..7 from xG (nbr)
#define LAYER256SR6(WF, ACC)                                                        \
  do {                                                                              \
    _Pragma("unroll") for (int ks = 0; ks < 8; ++ks)                                \
    _Pragma("unroll") for (int m = 0; m < 6; ++m) {                                 \
      const uint16_t* xb_ = (ks < 4) ? xE : xG;                                     \
      bf16x8 a_ = *(const bf16x8*)(xb_ + (m * 16 + l15) * MP + (ks & 3) * 32 + lg * 8); \
      ACC[m][0] = mfma16(a_, WF[ks], ACC[m][0]);                                    \
      ACC[m][1] = mfma16(a_, WF[8 + ks], ACC[m][1]);                                \
    }                                                                               \
  } while (0)

#define LAYER128R6(WF, ASRC, ACC)                                                   \
  do {                                                                              \
    _Pragma("unroll") for (int ks = 0; ks < 4; ++ks)                                \
    _Pragma("unroll") for (int m = 0; m < 6; ++m) {                                 \
      bf16x8 a_ = *(const bf16x8*)((ASRC) + (m * 16 + l15) * MP + ks * 32 + lg * 8);\
      ACC[m][0] = mfma16(a_, WF[ks], ACC[m][0]);                                    \
      ACC[m][1] = mfma16(a_, WF[4 + ks], ACC[m][1]);                                \
    }                                                                               \
  } while (0)

#define GSTORE6(ACC, BIAS, DST)                                                     \
  do {                                                                              \
    float bA_ = (BIAS)[w * 32 + l15];                                               \
    float bB_ = (BIAS)[w * 32 + 16 + l15];                                          \
    _Pragma("unroll") for (int m = 0; m < 6; ++m)                                   \
    _Pragma("unroll") for (int r = 0; r < 4; ++r) {                                 \
      int row_ = m * 16 + lg * 4 + r;                                               \
      (DST)[row_ * MP + w * 32 + l15] = f2b(gelu_f(ACC[m][0][r] + bA_));            \
      (DST)[row_ * MP + w * 32 + 16 + l15] = f2b(gelu_f(ACC[m][1][r] + bB_));       \
    }                                                                               \
  } while (0)

#define GSTORE06(ACC, DST)                                                          \
  do {                                                                              \
    _Pragma("unroll") for (int m = 0; m < 6; ++m)                                   \
    _Pragma("unroll") for (int r = 0; r < 4; ++r) {                                 \
      int row_ = m * 16 + lg * 4 + r;                                               \
      (DST)[row_ * MP + w * 32 + l15] = f2b(gelu_f(ACC[m][0][r]));                  \
      (DST)[row_ * MP + w * 32 + 16 + l15] = f2b(gelu_f(ACC[m][1][r]));             \
    }                                                                               \
  } while (0)

#define ACC_INIT6(ACC, CV)                                                          \
  do {                                                                              \
    float c0a_ = (CV)[(size_t)nd0 * 128 + w * 32 + l15];                            \
    float c1a_ = (CV)[(size_t)nd0 * 128 + w * 32 + 16 + l15];                       \
    float c0b_ = (CV)[(size_t)(nd0 + 1) * 128 + w * 32 + l15];                      \
    float c1b_ = (CV)[(size_t)(nd0 + 1) * 128 + w * 32 + 16 + l15];                 \
    _Pragma("unroll") for (int m = 0; m < 6; ++m) {                                 \
      float a_ = (m < 3) ? c0a_ : c0b_;                                             \
      float b_ = (m < 3) ? c1a_ : c1b_;                                             \
      ACC[m][0] = (f32x4){a_, a_, a_, a_};                                          \
      ACC[m][1] = (f32x4){b_, b_, b_, b_};                                          \
    }                                                                               \
  } while (0)

// ---------------- K1: node message MLP + masked sum + LN1 (r12 verbatim) ----------------
__global__ __launch_bounds__(256, 3) void k_node(
    const float* __restrict__ hV, const float* __restrict__ hE,
    const int* __restrict__ eidx, const float* __restrict__ maskA,
    const float* __restrict__ bias2, const float* __restrict__ bias3,
    const float* __restrict__ g1, const float* __restrict__ be1,
    const uint16_t* __restrict__ hVb, const float* __restrict__ C1,
    const uint16_t* __restrict__ W1t, const uint16_t* __restrict__ W2t,
    const uint16_t* __restrict__ W3t,
    float* __restrict__ hV1, uint16_t* __restrict__ hV1b) {
  __shared__ __align__(16) unsigned char lds[52608];
  uint16_t* xt = (uint16_t*)lds;
  uint16_t* midA = (uint16_t*)lds;             // overlays xt after post-L1 barrier
  uint16_t* midB = (uint16_t*)(lds + 26112);
  int* nbr = (int*)(lds + 52224);
  float* dh = (float*)lds;                     // [2][128], overlays dead midA

  const int tid = threadIdx.x;
  const int lane = tid & 63;
  const int w = tid >> 6;
  const int l15 = lane & 15;
  const int lg = lane >> 4;
  const int bid = ((blockIdx.x & 7) << 8) | (blockIdx.x >> 3);
  const int nd0 = bid * 2;
  const int base = bid * 96;                   // first edge row

  bf16x8 w1f[16];
  PRELOAD_W384(W1t, w1f);

  if (tid < 96) {
    int e = base + tid;
    nbr[tid] = ((e >= 98304) ? 2048 : 0) + eidx[e];
  }
  __syncthreads();

  BUILD_XT96(hVb);
  __syncthreads();

  f32x4 acc1[6][2];
  ACC_INIT6(acc1, C1);
  LAYER256R6(w1f, acc1);
  bf16x8 w2f[8];
  PRELOAD_W128(W2t, w2f);
  __syncthreads();               // all xt reads done; midA may overlay
  GSTORE06(acc1, midA);
  __syncthreads();

  f32x4 acc2[6][2] = {};
  LAYER128R6(w2f, midA, acc2);
  bf16x8 w3f[8];
  PRELOAD_W128(W3t, w3f);
  GSTORE6(acc2, bias2, midB);
  __syncthreads();               // midA reads done (dh overlay safe after this)

  f32x4 acc3[6][2] = {};
  LAYER128R6(w3f, midB, acc3);

  // masked column sums per node over its 48 rows
  {
    float bA = bias3[w * 32 + l15];
    float bB = bias3[w * 32 + 16 + l15];
    float s0a = 0.f, s1a = 0.f, s0b = 0.f, s1b = 0.f;
#pragma unroll
    for (int m = 0; m < 6; ++m)
#pragma unroll
      for (int r = 0; r < 4; ++r) {
        int row = m * 16 + lg * 4 + r;
        float mk = maskA[base + row];
        float v0 = (acc3[m][0][r] + bA) * mk;
        float v1 = (acc3[m][1][r] + bB) * mk;
        if (m < 3) { s0a += v0; s1a += v1; } else { s0b += v0; s1b += v1; }
      }
    s0a += __shfl_xor(s0a, 16); s0a += __shfl_xor(s0a, 32);
    s1a += __shfl_xor(s1a, 16); s1a += __shfl_xor(s1a, 32);
    s0b += __shfl_xor(s0b, 16); s0b += __shfl_xor(s0b, 32);
    s1b += __shfl_xor(s1b, 16); s1b += __shfl_xor(s1b, 32);
    if (lg == 0) {
      dh[w * 32 + l15] = s0a;        dh[w * 32 + 16 + l15] = s1a;
      dh[128 + w * 32 + l15] = s0b;  dh[128 + w * 32 + 16 + l15] = s1b;
    }
  }
  __syncthreads();

  if (w < 2) {
    int node = nd0 + w;
    const float inv = 1.0f / 30.0f;
    float x0 = hV[(size_t)node * 128 + lane] + dh[w * 128 + lane] * inv;
    float x1 = hV[(size_t)node * 128 + 64 + lane] + dh[w * 128 + 64 + lane] * inv;
    float s = x0 + x1, q = x0 * x0 + x1 * x1;
#pragma unroll
    for (int off = 1; off < 64; off <<= 1) {
      s += __shfl_xor(s, off);
      q += __shfl_xor(q, off);
    }
    float mean = s * (1.0f / 128.0f);
    float var = q * (1.0f / 128.0f) - mean * mean;
    float rstd = rsqrtf(var + 1e-5f);
    float y0 = (x0 - mean) * rstd * g1[lane] + be1[lane];
    float y1 = (x1 - mean) * rstd * g1[64 + lane] + be1[64 + lane];
    hV1[(size_t)node * 128 + lane] = y0;
    hV1[(size_t)node * 128 + 64 + lane] = y1;
    hV1b[(size_t)node * 128 + lane] = f2b(y0);
    hV1b[(size_t)node * 128 + 64 + lane] = f2b(y1);
  }
}

// ---------------- K2: position-wise FFN + LN2 + mask_V (r12 verbatim) ----------------
__global__ __launch_bounds__(256, 2) void k_ffn(
    const float* __restrict__ hV1, const uint16_t* __restrict__ hV1b,
    const float* __restrict__ maskV,
    const float* __restrict__ bdin, const float* __restrict__ bdout,
    const float* __restrict__ g2, const float* __restrict__ be2,
    const uint16_t* __restrict__ WdInT, const uint16_t* __restrict__ WdOutT,
    float* __restrict__ outV, uint16_t* __restrict__ hV2b) {
  __shared__ __align__(16) unsigned char lds[20992];
  uint16_t* xa = (uint16_t*)lds;             // [16][136]
  uint16_t* mf = (uint16_t*)(lds + 4352);    // [16][520]
  float* epi = (float*)(lds + 4352);         // [16][132] overlays mf (barrier-protected)

  const int tid = threadIdx.x;
  const int lane = tid & 63;
  const int w = tid >> 6;
  const int l15 = lane & 15;
  const int lg = lane >> 4;
  const int bid = ((blockIdx.x & 7) << 5) | (blockIdx.x >> 3);
  const int node0 = bid * 16;

  {
    int row = tid >> 4, c = tid & 15;
    *(uint4*)(xa + row * 136 + (c << 3)) =
        *(const uint4*)(hV1b + (node0 + row) * 128 + (c << 3));
  }
  __syncthreads();

  f32x4 acc[8] = {};
  {
    const uint16_t* ar = xa + l15 * 136 + lg * 8;
#pragma unroll
    for (int ks = 0; ks < 4; ++ks) {
      bf16x8 a = *(const bf16x8*)(ar + ks * 32);
#pragma unroll
      for (int j = 0; j < 8; ++j) {
        bf16x8 bb = *(const bf16x8*)(WdInT + ((w * 8 + j) * 16 + l15) * 128 + ks * 32 + lg * 8);
        acc[j] = mfma16(a, bb, acc[j]);
      }
    }
  }
#pragma unroll
  for (int j = 0; j < 8; ++j) {
    int col = (w * 8 + j) * 16 + l15;
    float bs = bdin[col];
#pragma unroll
    for (int r = 0; r < 4; ++r) {
      int row = lg * 4 + r;
      mf[row * FFP + col] = f2b(gelu_f(acc[j][r] + bs));
    }
  }
  __syncthreads();

  f32x4 acc2[2] = {};
  {
    const uint16_t* mr = mf + l15 * FFP + lg * 8;
#pragma unroll 4
    for (int ks = 0; ks < 16; ++ks) {
      bf16x8 a = *(const bf16x8*)(mr + ks * 32);
#pragma unroll
      for (int t = 0; t < 2; ++t) {
        bf16x8 bb = *(const bf16x8*)(WdOutT + ((w * 2 + t) * 16 + l15) * 512 + ks * 32 + lg * 8);
        acc2[t] = mfma16(a, bb, acc2[t]);
      }
    }
  }
  __syncthreads();
#pragma unroll
  for (int t = 0; t < 2; ++t) {
    int col = (w * 2 + t) * 16 + l15;
    float bs = bdout[col];
#pragma unroll
    for (int r = 0; r < 4; ++r) {
      int row = lg * 4 + r;
      epi[row * EPIP + col] = acc2[t][r] + bs;
    }
  }
  __syncthreads();

#pragma unroll
  for (int rr = 0; rr < 4; ++rr) {
    int row = w * 4 + rr;
    int node = node0 + row;
    float x0 = epi[row * EPIP + lane] + hV1[node * 128 + lane];
    float x1 = epi[row * EPIP + 64 + lane] + hV1[node * 128 + 64 + lane];
    float s = x0 + x1, q = x0 * x0 + x1 * x1;
#pragma unroll
    for (int off = 1; off < 64; off <<= 1) {
      s += __shfl_xor(s, off);
      q += __shfl_xor(q, off);
    }
    float mean = s * (1.0f / 128.0f);
    float var = q * (1.0f / 128.0f) - mean * mean;
    float rstd = rsqrtf(var + 1e-5f);
    float mv = maskV[node];
    float y0 = mv * ((x0 - mean) * rstd * g2[lane] + be2[lane]);
    float y1 = mv * ((x1 - mean) * rstd * g2[64 + lane] + be2[64 + lane]);
    outV[node * 128 + lane] = y0;
    outV[node * 128 + 64 + lane] = y1;
    hV2b[node * 128 + lane] = f2b(y0);
    hV2b[node * 128 + 64 + lane] = f2b(y1);
  }
}

// ---------------- K3: edge MLP + residual + LN3 (split tile, single mid) ----------------
// LDS map (52608 B total, verified):
//   xE  @0      [96][136] bf16 = 26112 B  (ALIVE to end; residual source)
//   xG  @26112  [96][136] bf16 = 26112 B  (ends 52224)
//   mid @26112  = overlays xG after layer-1 reads complete (same 26112 B)
//   nbr @52224  96*4 = 384 B              (ends 52608)
//   part_s @26112 [96][4] f32 = 1536 | part_q @27648 = 1536 | mstd @29184 = 768
//   (partials overlay mid AFTER the post-L3 barrier; all inside mid's 26112 B)
__global__ __launch_bounds__(256, 3) void k_edge(
    const float* __restrict__ hE, const int* __restrict__ eidx,
    const float* __restrict__ bias2, const float* __restrict__ bias3,
    const float* __restrict__ g3, const float* __restrict__ be3,
    const uint16_t* __restrict__ hV2b, const float* __restrict__ C2,
    const uint16_t* __restrict__ W1t, const uint16_t* __restrict__ W2t,
    const uint16_t* __restrict__ W3t,
    float* __restrict__ outE) {
  __shared__ __align__(16) unsigned char lds[52608];
  uint16_t* xE = (uint16_t*)lds;
  uint16_t* xG = (uint16_t*)(lds + 26112);
  uint16_t* mid = (uint16_t*)(lds + 26112);
  int* nbr = (int*)(lds + 52224);
  float* part_s = (float*)(lds + 26112);
  float* part_q = (float*)(lds + 27648);
  float* mstd = (float*)(lds + 29184);

  const int tid = threadIdx.x;
  const int lane = tid & 63;
  const int w = tid >> 6;
  const int l15 = lane & 15;
  const int lg = lane >> 4;
  const int bid = ((blockIdx.x & 7) << 8) | (blockIdx.x >> 3);
  const int nd0 = bid * 2;
  const int base = bid * 96;

  bf16x8 w1f[16];
  PRELOAD_W384(W1t, w1f);

  if (tid < 96) {
    int e = base + tid;
    nbr[tid] = ((e >= 98304) ? 2048 : 0) + eidx[e];
  }
  __syncthreads();

  BUILD_XT96S(hV2b);
  __syncthreads();

  f32x4 acc1[6][2];
  ACC_INIT6(acc1, C2);
  LAYER256SR6(w1f, acc1);
  bf16x8 w2f[8];
  PRELOAD_W128(W2t, w2f);
  __syncthreads();               // all xG reads done; mid may overlay xG
  GSTORE06(acc1, mid);
  __syncthreads();               // mid (L1 output) visible

  f32x4 acc2[6][2] = {};
  LAYER128R6(w2f, mid, acc2);
  bf16x8 w3f[8];
  PRELOAD_W128(W3t, w3f);
  __syncthreads();               // all mid reads done before overwrite
  GSTORE6(acc2, bias2, mid);
  __syncthreads();               // mid (L2 output) visible

  f32x4 acc3[6][2] = {};
  LAYER128R6(w3f, mid, acc3);
  __syncthreads();               // all mid reads done; partials overlay safe

  const float bA = bias3[w * 32 + l15];
  const float bB = bias3[w * 32 + 16 + l15];

  // x = acc3 + bias + hE residual (bf16 from live xE tile), cached in VGPRs
  float xs0[6][4], xs1[6][4];
#pragma unroll
  for (int m = 0; m < 6; ++m)
#pragma unroll
    for (int r = 0; r < 4; ++r) {
      int row = m * 16 + lg * 4 + r;
      xs0[m][r] = acc3[m][0][r] + bA + b2f(xE[row * MP + w * 32 + l15]);
      xs1[m][r] = acc3[m][1][r] + bB + b2f(xE[row * MP + w * 32 + 16 + l15]);
      float s = xs0[m][r] + xs1[m][r];
      float q = xs0[m][r] * xs0[m][r] + xs1[m][r] * xs1[m][r];
      s += __shfl_xor(s, 1); q += __shfl_xor(q, 1);
      s += __shfl_xor(s, 2); q += __shfl_xor(q, 2);
      s += __shfl_xor(s, 4); q += __shfl_xor(q, 4);
      s += __shfl_xor(s, 8); q += __shfl_xor(q, 8);
      if (l15 == 0) { part_s[row * 4 + w] = s; part_q[row * 4 + w] = q; }
    }
  __syncthreads();

  if (tid < 96) {
    float s = part_s[tid * 4] + part_s[tid * 4 + 1] + part_s[tid * 4 + 2] + part_s[tid * 4 + 3];
    float q = part_q[tid * 4] + part_q[tid * 4 + 1] + part_q[tid * 4 + 2] + part_q[tid * 4 + 3];
    float mean = s * (1.0f / 128.0f);
    float var = q * (1.0f / 128.0f) - mean * mean;
    mstd[tid * 2] = mean;
    mstd[tid * 2 + 1] = rsqrtf(var + 1e-5f);
  }
  __syncthreads();

  const float gA = g3[w * 32 + l15], beA = be3[w * 32 + l15];
  const float gB = g3[w * 32 + 16 + l15], beB = be3[w * 32 + 16 + l15];
#pragma unroll
  for (int m = 0; m < 6; ++m)
#pragma unroll
    for (int r = 0; r < 4; ++r) {
      int row = m * 16 + lg * 4 + r;
      size_t e = (size_t)base + row;
      float mean = mstd[row * 2];
      float rstd = mstd[row * 2 + 1];
      outE[e * 128 + w * 32 + l15] = (xs0[m][r] - mean) * rstd * gA + beA;
      outE[e * 128 + w * 32 + 16 + l15] = (xs1[m][r] - mean) * rstd * gB + beB;
    }
}

extern "C" void kernel_launch(void* const* d_in, const int* in_sizes, int n_in,
                              void* d_out, int out_size, void* d_ws, size_t ws_size,
                              hipStream_t stream) {
  const float* hV = (const float*)d_in[0];
  const float* hE = (const float*)d_in[1];
  const int* eidx = (const int*)d_in[2];
  const float* maskV = (const float*)d_in[3];
  const float* maskA = (const float*)d_in[4];
  const float* W1 = (const float*)d_in[5];   const float* b1 = (const float*)d_in[6];
  const float* W2 = (const float*)d_in[7];   const float* b2 = (const float*)d_in[8];
  const float* W3 = (const float*)d_in[9];   const float* b3 = (const float*)d_in[10];
  const float* WdIn = (const float*)d_in[11];  const float* bdin = (const float*)d_in[12];
  const float* WdOut = (const float*)d_in[13]; const float* bdout = (const float*)d_in[14];
  const float* W11 = (const float*)d_in[15]; const float* b11 = (const float*)d_in[16];
  const float* W12 = (const float*)d_in[17]; const float* b12 = (const float*)d_in[18];
  const float* W13 = (const float*)d_in[19]; const float* b13 = (const float*)d_in[20];
  const float* n1g = (const float*)d_in[21]; const float* n1b = (const float*)d_in[22];
  const float* n2g = (const float*)d_in[23]; const float* n2b = (const float*)d_in[24];
  const float* n3g = (const float*)d_in[25]; const float* n3b = (const float*)d_in[26];

  char* ws = (char*)d_ws;
  uint16_t* hVb    = (uint16_t*)(ws + 0);
  uint16_t* W1t    = (uint16_t*)(ws + 1048576);
  uint16_t* W2t    = (uint16_t*)(ws + 1146880);
  uint16_t* W3t    = (uint16_t*)(ws + 1179648);
  uint16_t* WdInT  = (uint16_t*)(ws + 1212416);
  uint16_t* WdOutT = (uint16_t*)(ws + 1343488);
  uint16_t* W11t   = (uint16_t*)(ws + 1474560);
  uint16_t* W12t   = (uint16_t*)(ws + 1572864);
  uint16_t* W13t   = (uint16_t*)(ws + 1605632);
  float*    hV1    = (float*)(ws + 1638400);
  uint16_t* hV1b   = (uint16_t*)(ws + 3735552);
  uint16_t* hV2b   = (uint16_t*)(ws + 4784128);
  float*    C1     = (float*)(ws + 5832704);
  float*    C2     = (float*)(ws + 7929856);

  float* outV = (float*)d_out;
  float* outE = (float*)d_out + 524288;

  k_prep<<<3200, 256, 0, stream>>>(hV, W1, W2, W3, WdIn, WdOut, W11, W12, W13,
                                   hVb, W1t, W2t, W3t, WdInT, WdOutT, W11t, W12t, W13t);
  k_vec<<<64, 256, 0, stream>>>(hVb, W1t, b1, C1);
  k_node<<<2048, 256, 0, stream>>>(hV, hE, eidx, maskA, b2, b3, n1g, n1b,
                                   hVb, C1, W1t, W2t, W3t, hV1, hV1b);
  k_ffn<<<256, 256, 0, stream>>>(hV1, hV1b, maskV, bdin, bdout, n2g, n2b,
                                 WdInT, WdOutT, outV, hV2b);
  k_vec<<<64, 256, 0, stream>>>(hV2b, W11t, b11, C2);
  k_edge<<<2048, 256, 0, stream>>>(hE, eidx, b12, b13, n3g, n3b,
                                   hV2b, C2, W11t, W12t, W13t, outE);
}

// Round 16
// 208.308 us; speedup vs baseline: 1.3915x; 1.0049x over previous
//
#include <hip/hip_runtime.h>
#include <hip/hip_bf16.h>
#include <stdint.h>

// Problem constants: B=2, N=2048, K=48, H=128, 3H=384, FF=512
// 2 nodes per block: 96 edge rows, 4 waves, wave w owns out-cols w*32..w*32+31.
#define XP2 264     // k_node x_tile pitch (bf16)
#define MP 136      // split-tile / mid pitch (bf16): 68 dwords (68%32=4)
#define FFP 520     // ffn mid pitch
#define EPIP 132

typedef __attribute__((ext_vector_type(8))) short bf16x8;
typedef __attribute__((ext_vector_type(4))) float f32x4;

__device__ __forceinline__ f32x4 mfma16(bf16x8 a, bf16x8 b, f32x4 c) {
  return __builtin_amdgcn_mfma_f32_16x16x32_bf16(a, b, c, 0, 0, 0);
}

__device__ __forceinline__ uint16_t f2b(float f) {
  union { __hip_bfloat16 h; uint16_t u; } v;
  v.h = __float2bfloat16(f);
  return v.u;
}
__device__ __forceinline__ float b2f(uint16_t h) {
  union { uint32_t u; float f; } v; v.u = ((uint32_t)h) << 16;
  return v.f;
}
__device__ __forceinline__ uint32_t pk2f(float a, float b) {
  union { __hip_bfloat162 h; uint32_t u; } v;
  v.h = __float22bfloat162_rn(make_float2(a, b));
  return v.u;
}
__device__ __forceinline__ float gelu_f(float x) {
  float u = __builtin_fmaf(x * x, 0.044715f, 1.0f);
  float e = __builtin_amdgcn_exp2f(-2.302585093f * x * u);
  return x * __builtin_amdgcn_rcpf(1.0f + e);
}

// ---------------- prep: bf16 h_V + transposed bf16 weights ----------------
__global__ __launch_bounds__(256) void k_prep(
    const float* __restrict__ hV,
    const float* __restrict__ W1, const float* __restrict__ W2, const float* __restrict__ W3,
    const float* __restrict__ WdIn, const float* __restrict__ WdOut,
    const float* __restrict__ W11, const float* __restrict__ W12, const float* __restrict__ W13,
    uint16_t* __restrict__ hVb,
    uint16_t* __restrict__ W1t, uint16_t* __restrict__ W2t, uint16_t* __restrict__ W3t,
    uint16_t* __restrict__ WdInT, uint16_t* __restrict__ WdOutT,
    uint16_t* __restrict__ W11t, uint16_t* __restrict__ W12t, uint16_t* __restrict__ W13t) {
  int i = blockIdx.x * 256 + threadIdx.x;
  if (i < 524288) { hVb[i] = f2b(hV[i]); return; }
  int j = i - 524288;
  if (j < 49152) { int n = j / 384, k = j - n * 384; W1t[j] = f2b(W1[k * 128 + n]); return; }
  j -= 49152;
  if (j < 16384) { int n = j >> 7, k = j & 127; W2t[j] = f2b(W2[k * 128 + n]); return; }
  j -= 16384;
  if (j < 16384) { int n = j >> 7, k = j & 127; W3t[j] = f2b(W3[k * 128 + n]); return; }
  j -= 16384;
  if (j < 65536) { int n = j >> 7, k = j & 127; WdInT[j] = f2b(WdIn[k * 512 + n]); return; }
  j -= 65536;
  if (j < 65536) { int n = j >> 9, k = j & 511; WdOutT[j] = f2b(WdOut[k * 128 + n]); return; }
  j -= 65536;
  if (j < 49152) { int n = j / 384, k = j - n * 384; W11t[j] = f2b(W11[k * 128 + n]); return; }
  j -= 49152;
  if (j < 16384) { int n = j >> 7, k = j & 127; W12t[j] = f2b(W12[k * 128 + n]); return; }
  j -= 16384;
  if (j < 16384) { int n = j >> 7, k = j & 127; W13t[j] = f2b(W13[k * 128 + n]); return; }
}

// ---------------- prep2: streaming hE f32 -> bf16 (25,165,824 elems) ----------------
__global__ __launch_bounds__(256) void k_prep2(
    const float* __restrict__ hE, uint16_t* __restrict__ hEb) {
  size_t i = ((size_t)blockIdx.x * 256 + threadIdx.x) * 8;
  float4 f0 = *(const float4*)(hE + i);
  float4 f1 = *(const float4*)(hE + i + 4);
  uint4 v = make_uint4(pk2f(f0.x, f0.y), pk2f(f0.z, f0.w),
                       pk2f(f1.x, f1.y), pk2f(f1.z, f1.w));
  *(uint4*)(hEb + i) = v;
}

// ------- k_vec: C[i][n] = sum_{k<128} Xb[i][k]*Wt[n][k] + bias[n] -------
__global__ __launch_bounds__(256) void k_vec(
    const uint16_t* __restrict__ Xb, const uint16_t* __restrict__ Wt,
    const float* __restrict__ bias, float* __restrict__ C) {
  const int tid = threadIdx.x;
  const int lane = tid & 63, w = tid >> 6, l15 = lane & 15, lg = lane >> 4;
  const int row0 = blockIdx.x * 64 + w * 16;
  f32x4 acc[8] = {};
#pragma unroll
  for (int ks = 0; ks < 4; ++ks) {
    bf16x8 a = *(const bf16x8*)(Xb + (row0 + l15) * 128 + ks * 32 + lg * 8);
#pragma unroll
    for (int j = 0; j < 8; ++j) {
      bf16x8 bb = *(const bf16x8*)(Wt + (j * 16 + l15) * 384 + ks * 32 + lg * 8);
      acc[j] = mfma16(a, bb, acc[j]);
    }
  }
#pragma unroll
  for (int j = 0; j < 8; ++j) {
    float bs = bias[j * 16 + l15];
#pragma unroll
    for (int r = 0; r < 4; ++r)
      C[(row0 + lg * 4 + r) * 128 + j * 16 + l15] = acc[j][r] + bs;
  }
}

// ===== 96-row block-staged MLP macros =====
#define PRELOAD_W384(WT, WF)                                                        \
  do {                                                                              \
    const uint16_t* p0_ = (WT) + (w * 32 + l15) * 384 + 128 + lg * 8;               \
    const uint16_t* p1_ = p0_ + 16 * 384;                                           \
    _Pragma("unroll") for (int ks = 0; ks < 8; ++ks) {                              \
      WF[ks] = *(const bf16x8*)(p0_ + ks * 32);                                     \
      WF[8 + ks] = *(const bf16x8*)(p1_ + ks * 32);                                 \
    }                                                                               \
  } while (0)

#define PRELOAD_W128(WT, WF)                                                        \
  do {                                                                              \
    const uint16_t* p0_ = (WT) + (w * 32 + l15) * 128 + lg * 8;                     \
    const uint16_t* p1_ = p0_ + 16 * 128;                                           \
    _Pragma("unroll") for (int ks = 0; ks < 4; ++ks) {                              \
      WF[ks] = *(const bf16x8*)(p0_ + ks * 32);                                     \
      WF[4 + ks] = *(const bf16x8*)(p1_ + ks * 32);                                 \
    }                                                                               \
  } while (0)

#define LAYER256R6(WF, ACC)                                                         \
  do {                                                                              \
    _Pragma("unroll") for (int ks = 0; ks < 8; ++ks)                                \
    _Pragma("unroll") for (int m = 0; m < 6; ++m) {                                 \
      bf16x8 a_ = *(const bf16x8*)(xt + (m * 16 + l15) * XP2 + ks * 32 + lg * 8);   \
      ACC[m][0] = mfma16(a_, WF[ks], ACC[m][0]);                                    \
      ACC[m][1] = mfma16(a_, WF[8 + ks], ACC[m][1]);                                \
    }                                                                               \
  } while (0)

#define LAYER256SR6(WF, ACC)                                                        \
  do {                                                                              \
    _Pragma("unroll") for (int ks = 0; ks < 8; ++ks)                                \
    _Pragma("unroll") for (int m = 0; m < 6; ++m) {                                 \
      const uint16_t* xb_ = (ks < 4) ? xE : xG;                                     \
      bf16x8 a_ = *(const bf16x8*)(xb_ + (m * 16 + l15) * MP + (ks & 3) * 32 + lg * 8); \
      ACC[m][0] = mfma16(a_, WF[ks], ACC[m][0]);                                    \
      ACC[m][1] = mfma16(a_, WF[8 + ks], ACC[m][1]);                                \
    }                                                                               \
  } while (0)

#define LAYER128R6(WF, ASRC, ACC)                                                   \
  do {                                                                              \
    _Pragma("unroll") for (int ks = 0; ks < 4; ++ks)                                \
    _Pragma("unroll") for (int m = 0; m < 6; ++m) {                                 \
      bf16x8 a_ = *(const bf16x8*)((ASRC) + (m * 16 + l15) * MP + ks * 32 + lg * 8);\
      ACC[m][0] = mfma16(a_, WF[ks], ACC[m][0]);                                    \
      ACC[m][1] = mfma16(a_, WF[4 + ks], ACC[m][1]);                                \
    }                                                                               \
  } while (0)

#define GSTORE6(ACC, BIAS, DST)                                                     \
  do {                                                                              \
    float bA_ = (BIAS)[w * 32 + l15];                                               \
    float bB_ = (BIAS)[w * 32 + 16 + l15];                                          \
    _Pragma("unroll") for (int m = 0; m < 6; ++m)                                   \
    _Pragma("unroll") for (int r = 0; r < 4; ++r) {                                 \
      int row_ = m * 16 + lg * 4 + r;                                               \
      (DST)[row_ * MP + w * 32 + l15] = f2b(gelu_f(ACC[m][0][r] + bA_));            \
      (DST)[row_ * MP + w * 32 + 16 + l15] = f2b(gelu_f(ACC[m][1][r] + bB_));       \
    }                                                                               \
  } while (0)

#define GSTORE06(ACC, DST)                                                          \
  do {                                                                              \
    _Pragma("unroll") for (int m = 0; m < 6; ++m)                                   \
    _Pragma("unroll") for (int r = 0; r < 4; ++r) {                                 \
      int row_ = m * 16 + lg * 4 + r;                                               \
      (DST)[row_ * MP + w * 32 + l15] = f2b(gelu_f(ACC[m][0][r]));                  \
      (DST)[row_ * MP + w * 32 + 16 + l15] = f2b(gelu_f(ACC[m][1][r]));             \
    }                                                                               \
  } while (0)

#define ACC_INIT6(ACC, CV)                                                          \
  do {                                                                              \
    float c0a_ = (CV)[(size_t)nd0 * 128 + w * 32 + l15];                            \
    float c1a_ = (CV)[(size_t)nd0 * 128 + w * 32 + 16 + l15];                       \
    float c0b_ = (CV)[(size_t)(nd0 + 1) * 128 + w * 32 + l15];                      \
    float c1b_ = (CV)[(size_t)(nd0 + 1) * 128 + w * 32 + 16 + l15];                 \
    _Pragma("unroll") for (int m = 0; m < 6; ++m) {                                 \
      float a_ = (m < 3) ? c0a_ : c0b_;                                             \
      float b_ = (m < 3) ? c1a_ : c1b_;                                             \
      ACC[m][0] = (f32x4){a_, a_, a_, a_};                                          \
      ACC[m][1] = (f32x4){b_, b_, b_, b_};                                          \
    }                                                                               \
  } while (0)

// ---------------- K1: node message MLP + masked sum + LN1 ----------------
// BF=true: stage from pre-converted bf16 hEb (uniform uint4 copies).
// BF=false: r15-verified f32+cvt path.
template <bool BF>
__global__ __launch_bounds__(256, 3) void k_node_t(
    const float* __restrict__ hV, const float* __restrict__ hE,
    const uint16_t* __restrict__ hEb,
    const int* __restrict__ eidx, const float* __restrict__ maskA,
    const float* __restrict__ bias2, const float* __restrict__ bias3,
    const float* __restrict__ g1, const float* __restrict__ be1,
    const uint16_t* __restrict__ hVb, const float* __restrict__ C1,
    const uint16_t* __restrict__ W1t, const uint16_t* __restrict__ W2t,
    const uint16_t* __restrict__ W3t,
    float* __restrict__ hV1, uint16_t* __restrict__ hV1b) {
  __shared__ __align__(16) unsigned char lds[52608];
  uint16_t* xt = (uint16_t*)lds;
  uint16_t* midA = (uint16_t*)lds;             // overlays xt after post-L1 barrier
  uint16_t* midB = (uint16_t*)(lds + 26112);
  int* nbr = (int*)(lds + 52224);
  float* dh = (float*)lds;                     // [2][128], overlays dead midA

  const int tid = threadIdx.x;
  const int lane = tid & 63;
  const int w = tid >> 6;
  const int l15 = lane & 15;
  const int lg = lane >> 4;
  const int bid = ((blockIdx.x & 7) << 8) | (blockIdx.x >> 3);
  const int nd0 = bid * 2;
  const int base = bid * 96;                   // first edge row

  bf16x8 w1f[16];
  PRELOAD_W384(W1t, w1f);

  if (tid < 96) {
    int e = base + tid;
    nbr[tid] = ((e >= 98304) ? 2048 : 0) + eidx[e];
  }
  __syncthreads();

  // staging
  for (int idx = tid; idx < 96 * 32; idx += 256) {
    int k_ = idx >> 5;
    int c_ = idx & 31;
    if constexpr (BF) {
      const uint16_t* s_ = (c_ < 16)
          ? hEb + (size_t)(base + k_) * 128 + (c_ << 3)
          : hVb + (size_t)nbr[k_] * 128 + ((c_ - 16) << 3);
      *(uint4*)(xt + k_ * XP2 + (c_ << 3)) = *(const uint4*)s_;
    } else {
      uint4 v_;
      if (c_ < 16) {
        const float* s_ = hE + (size_t)(base + k_) * 128 + (c_ << 3);
        float4 f0_ = *(const float4*)s_;
        float4 f1_ = *(const float4*)(s_ + 4);
        v_ = make_uint4(pk2f(f0_.x, f0_.y), pk2f(f0_.z, f0_.w),
                        pk2f(f1_.x, f1_.y), pk2f(f1_.z, f1_.w));
      } else {
        v_ = *(const uint4*)(hVb + (size_t)nbr[k_] * 128 + ((c_ - 16) << 3));
      }
      *(uint4*)(xt + k_ * XP2 + (c_ << 3)) = v_;
    }
  }
  __syncthreads();

  f32x4 acc1[6][2];
  ACC_INIT6(acc1, C1);
  LAYER256R6(w1f, acc1);
  bf16x8 w2f[8];
  PRELOAD_W128(W2t, w2f);
  __syncthreads();               // all xt reads done; midA may overlay
  GSTORE06(acc1, midA);
  __syncthreads();

  f32x4 acc2[6][2] = {};
  LAYER128R6(w2f, midA, acc2);
  bf16x8 w3f[8];
  PRELOAD_W128(W3t, w3f);
  GSTORE6(acc2, bias2, midB);
  __syncthreads();               // midA reads done (dh overlay safe after this)

  f32x4 acc3[6][2] = {};
  LAYER128R6(w3f, midB, acc3);

  // masked column sums per node over its 48 rows
  {
    float bA = bias3[w * 32 + l15];
    float bB = bias3[w * 32 + 16 + l15];
    float s0a = 0.f, s1a = 0.f, s0b = 0.f, s1b = 0.f;
#pragma unroll
    for (int m = 0; m < 6; ++m)
#pragma unroll
      for (int r = 0; r < 4; ++r) {
        int row = m * 16 + lg * 4 + r;
        float mk = maskA[base + row];
        float v0 = (acc3[m][0][r] + bA) * mk;
        float v1 = (acc3[m][1][r] + bB) * mk;
        if (m < 3) { s0a += v0; s1a += v1; } else { s0b += v0; s1b += v1; }
      }
    s0a += __shfl_xor(s0a, 16); s0a += __shfl_xor(s0a, 32);
    s1a += __shfl_xor(s1a, 16); s1a += __shfl_xor(s1a, 32);
    s0b += __shfl_xor(s0b, 16); s0b += __shfl_xor(s0b, 32);
    s1b += __shfl_xor(s1b, 16); s1b += __shfl_xor(s1b, 32);
    if (lg == 0) {
      dh[w * 32 + l15] = s0a;        dh[w * 32 + 16 + l15] = s1a;
      dh[128 + w * 32 + l15] = s0b;  dh[128 + w * 32 + 16 + l15] = s1b;
    }
  }
  __syncthreads();

  if (w < 2) {
    int node = nd0 + w;
    const float inv = 1.0f / 30.0f;
    float x0 = hV[(size_t)node * 128 + lane] + dh[w * 128 + lane] * inv;
    float x1 = hV[(size_t)node * 128 + 64 + lane] + dh[w * 128 + 64 + lane] * inv;
    float s = x0 + x1, q = x0 * x0 + x1 * x1;
#pragma unroll
    for (int off = 1; off < 64; off <<= 1) {
      s += __shfl_xor(s, off);
      q += __shfl_xor(q, off);
    }
    float mean = s * (1.0f / 128.0f);
    float var = q * (1.0f / 128.0f) - mean * mean;
    float rstd = rsqrtf(var + 1e-5f);
    float y0 = (x0 - mean) * rstd * g1[lane] + be1[lane];
    float y1 = (x1 - mean) * rstd * g1[64 + lane] + be1[64 + lane];
    hV1[(size_t)node * 128 + lane] = y0;
    hV1[(size_t)node * 128 + 64 + lane] = y1;
    hV1b[(size_t)node * 128 + lane] = f2b(y0);
    hV1b[(size_t)node * 128 + 64 + lane] = f2b(y1);
  }
}

// ---------------- K2: position-wise FFN + LN2 + mask_V (r15 verbatim) ----------------
__global__ __launch_bounds__(256, 2) void k_ffn(
    const float* __restrict__ hV1, const uint16_t* __restrict__ hV1b,
    const float* __restrict__ maskV,
    const float* __restrict__ bdin, const float* __restrict__ bdout,
    const float* __restrict__ g2, const float* __restrict__ be2,
    const uint16_t* __restrict__ WdInT, const uint16_t* __restrict__ WdOutT,
    float* __restrict__ outV, uint16_t* __restrict__ hV2b) {
  __shared__ __align__(16) unsigned char lds[20992];
  uint16_t* xa = (uint16_t*)lds;             // [16][136]
  uint16_t* mf = (uint16_t*)(lds + 4352);    // [16][520]
  float* epi = (float*)(lds + 4352);         // [16][132] overlays mf (barrier-protected)

  const int tid = threadIdx.x;
  const int lane = tid & 63;
  const int w = tid >> 6;
  const int l15 = lane & 15;
  const int lg = lane >> 4;
  const int bid = ((blockIdx.x & 7) << 5) | (blockIdx.x >> 3);
  const int node0 = bid * 16;

  {
    int row = tid >> 4, c = tid & 15;
    *(uint4*)(xa + row * 136 + (c << 3)) =
        *(const uint4*)(hV1b + (node0 + row) * 128 + (c << 3));
  }
  __syncthreads();

  f32x4 acc[8] = {};
  {
    const uint16_t* ar = xa + l15 * 136 + lg * 8;
#pragma unroll
    for (int ks = 0; ks < 4; ++ks) {
      bf16x8 a = *(const bf16x8*)(ar + ks * 32);
#pragma unroll
      for (int j = 0; j < 8; ++j) {
        bf16x8 bb = *(const bf16x8*)(WdInT + ((w * 8 + j) * 16 + l15) * 128 + ks * 32 + lg * 8);
        acc[j] = mfma16(a, bb, acc[j]);
      }
    }
  }
#pragma unroll
  for (int j = 0; j < 8; ++j) {
    int col = (w * 8 + j) * 16 + l15;
    float bs = bdin[col];
#pragma unroll
    for (int r = 0; r < 4; ++r) {
      int row = lg * 4 + r;
      mf[row * FFP + col] = f2b(gelu_f(acc[j][r] + bs));
    }
  }
  __syncthreads();

  f32x4 acc2[2] = {};
  {
    const uint16_t* mr = mf + l15 * FFP + lg * 8;
#pragma unroll 4
    for (int ks = 0; ks < 16; ++ks) {
      bf16x8 a = *(const bf16x8*)(mr + ks * 32);
#pragma unroll
      for (int t = 0; t < 2; ++t) {
        bf16x8 bb = *(const bf16x8*)(WdOutT + ((w * 2 + t) * 16 + l15) * 512 + ks * 32 + lg * 8);
        acc2[t] = mfma16(a, bb, acc2[t]);
      }
    }
  }
  __syncthreads();
#pragma unroll
  for (int t = 0; t < 2; ++t) {
    int col = (w * 2 + t) * 16 + l15;
    float bs = bdout[col];
#pragma unroll
    for (int r = 0; r < 4; ++r) {
      int row = lg * 4 + r;
      epi[row * EPIP + col] = acc2[t][r] + bs;
    }
  }
  __syncthreads();

#pragma unroll
  for (int rr = 0; rr < 4; ++rr) {
    int row = w * 4 + rr;
    int node = node0 + row;
    float x0 = epi[row * EPIP + lane] + hV1[node * 128 + lane];
    float x1 = epi[row * EPIP + 64 + lane] + hV1[node * 128 + 64 + lane];
    float s = x0 + x1, q = x0 * x0 + x1 * x1;
#pragma unroll
    for (int off = 1; off < 64; off <<= 1) {
      s += __shfl_xor(s, off);
      q += __shfl_xor(q, off);
    }
    float mean = s * (1.0f / 128.0f);
    float var = q * (1.0f / 128.0f) - mean * mean;
    float rstd = rsqrtf(var + 1e-5f);
    float mv = maskV[node];
    float y0 = mv * ((x0 - mean) * rstd * g2[lane] + be2[lane]);
    float y1 = mv * ((x1 - mean) * rstd * g2[64 + lane] + be2[64 + lane]);
    outV[node * 128 + lane] = y0;
    outV[node * 128 + 64 + lane] = y1;
    hV2b[node * 128 + lane] = f2b(y0);
    hV2b[node * 128 + 64 + lane] = f2b(y1);
  }
}

// ---------------- K3: edge MLP + residual + LN3 (r15-verified, templated staging) ----------------
// LDS map (52608 B): xE @0 (26112, alive to end) | xG/mid @26112 (26112) | nbr @52224
template <bool BF>
__global__ __launch_bounds__(256, 3) void k_edge_t(
    const float* __restrict__ hE, const uint16_t* __restrict__ hEb,
    const int* __restrict__ eidx,
    const float* __restrict__ bias2, const float* __restrict__ bias3,
    const float* __restrict__ g3, const float* __restrict__ be3,
    const uint16_t* __restrict__ hV2b, const float* __restrict__ C2,
    const uint16_t* __restrict__ W1t, const uint16_t* __restrict__ W2t,
    const uint16_t* __restrict__ W3t,
    float* __restrict__ outE) {
  __shared__ __align__(16) unsigned char lds[52608];
  uint16_t* xE = (uint16_t*)lds;
  uint16_t* xG = (uint16_t*)(lds + 26112);
  uint16_t* mid = (uint16_t*)(lds + 26112);
  int* nbr = (int*)(lds + 52224);
  float* part_s = (float*)(lds + 26112);
  float* part_q = (float*)(lds + 27648);
  float* mstd = (float*)(lds + 29184);

  const int tid = threadIdx.x;
  const int lane = tid & 63;
  const int w = tid >> 6;
  const int l15 = lane & 15;
  const int lg = lane >> 4;
  const int bid = ((blockIdx.x & 7) << 8) | (blockIdx.x >> 3);
  const int nd0 = bid * 2;
  const int base = bid * 96;

  bf16x8 w1f[16];
  PRELOAD_W384(W1t, w1f);

  if (tid < 96) {
    int e = base + tid;
    nbr[tid] = ((e >= 98304) ? 2048 : 0) + eidx[e];
  }
  __syncthreads();

  // split staging: hE half -> xE, gather half -> xG
  for (int idx = tid; idx < 96 * 32; idx += 256) {
    int k_ = idx >> 5;
    int c_ = idx & 31;
    if constexpr (BF) {
      const uint16_t* s_ = (c_ < 16)
          ? hEb + (size_t)(base + k_) * 128 + (c_ << 3)
          : hV2b + (size_t)nbr[k_] * 128 + ((c_ - 16) << 3);
      uint16_t* d_ = (c_ < 16)
          ? xE + k_ * MP + (c_ << 3)
          : xG + k_ * MP + ((c_ - 16) << 3);
      *(uint4*)d_ = *(const uint4*)s_;
    } else {
      if (c_ < 16) {
        const float* s_ = hE + (size_t)(base + k_) * 128 + (c_ << 3);
        float4 f0_ = *(const float4*)s_;
        float4 f1_ = *(const float4*)(s_ + 4);
        uint4 v_ = make_uint4(pk2f(f0_.x, f0_.y), pk2f(f0_.z, f0_.w),
                              pk2f(f1_.x, f1_.y), pk2f(f1_.z, f1_.w));
        *(uint4*)(xE + k_ * MP + (c_ << 3)) = v_;
      } else {
        uint4 v_ = *(const uint4*)(hV2b + (size_t)nbr[k_] * 128 + ((c_ - 16) << 3));
        *(uint4*)(xG + k_ * MP + ((c_ - 16) << 3)) = v_;
      }
    }
  }
  __syncthreads();

  f32x4 acc1[6][2];
  ACC_INIT6(acc1, C2);
  LAYER256SR6(w1f, acc1);
  bf16x8 w2f[8];
  PRELOAD_W128(W2t, w2f);
  __syncthreads();               // all xG reads done; mid may overlay xG
  GSTORE06(acc1, mid);
  __syncthreads();               // mid (L1 output) visible

  f32x4 acc2[6][2] = {};
  LAYER128R6(w2f, mid, acc2);
  bf16x8 w3f[8];
  PRELOAD_W128(W3t, w3f);
  __syncthreads();               // all mid reads done before overwrite
  GSTORE6(acc2, bias2, mid);
  __syncthreads();               // mid (L2 output) visible

  f32x4 acc3[6][2] = {};
  LAYER128R6(w3f, mid, acc3);
  __syncthreads();               // all mid reads done; partials overlay safe

  const float bA = bias3[w * 32 + l15];
  const float bB = bias3[w * 32 + 16 + l15];

  // x = acc3 + bias + hE residual (bf16 from live xE tile), cached in VGPRs
  float xs0[6][4], xs1[6][4];
#pragma unroll
  for (int m = 0; m < 6; ++m)
#pragma unroll
    for (int r = 0; r < 4; ++r) {
      int row = m * 16 + lg * 4 + r;
      xs0[m][r] = acc3[m][0][r] + bA + b2f(xE[row * MP + w * 32 + l15]);
      xs1[m][r] = acc3[m][1][r] + bB + b2f(xE[row * MP + w * 32 + 16 + l15]);
      float s = xs0[m][r] + xs1[m][r];
      float q = xs0[m][r] * xs0[m][r] + xs1[m][r] * xs1[m][r];
      s += __shfl_xor(s, 1); q += __shfl_xor(q, 1);
      s += __shfl_xor(s, 2); q += __shfl_xor(q, 2);
      s += __shfl_xor(s, 4); q += __shfl_xor(q, 4);
      s += __shfl_xor(s, 8); q += __shfl_xor(q, 8);
      if (l15 == 0) { part_s[row * 4 + w] = s; part_q[row * 4 + w] = q; }
    }
  __syncthreads();

  if (tid < 96) {
    float s = part_s[tid * 4] + part_s[tid * 4 + 1] + part_s[tid * 4 + 2] + part_s[tid * 4 + 3];
    float q = part_q[tid * 4] + part_q[tid * 4 + 1] + part_q[tid * 4 + 2] + part_q[tid * 4 + 3];
    float mean = s * (1.0f / 128.0f);
    float var = q * (1.0f / 128.0f) - mean * mean;
    mstd[tid * 2] = mean;
    mstd[tid * 2 + 1] = rsqrtf(var + 1e-5f);
  }
  __syncthreads();

  const float gA = g3[w * 32 + l15], beA = be3[w * 32 + l15];
  const float gB = g3[w * 32 + 16 + l15], beB = be3[w * 32 + 16 + l15];
#pragma unroll
  for (int m = 0; m < 6; ++m)
#pragma unroll
    for (int r = 0; r < 4; ++r) {
      int row = m * 16 + lg * 4 + r;
      size_t e = (size_t)base + row;
      float mean = mstd[row * 2];
      float rstd = mstd[row * 2 + 1];
      outE[e * 128 + w * 32 + l15] = (xs0[m][r] - mean) * rstd * gA + beA;
      outE[e * 128 + w * 32 + 16 + l15] = (xs1[m][r] - mean) * rstd * gB + beB;
    }
}

extern "C" void kernel_launch(void* const* d_in, const int* in_sizes, int n_in,
                              void* d_out, int out_size, void* d_ws, size_t ws_size,
                              hipStream_t stream) {
  const float* hV = (const float*)d_in[0];
  const float* hE = (const float*)d_in[1];
  const int* eidx = (const int*)d_in[2];
  const float* maskV = (const float*)d_in[3];
  const float* maskA = (const float*)d_in[4];
  const float* W1 = (const float*)d_in[5];   const float* b1 = (const float*)d_in[6];
  const float* W2 = (const float*)d_in[7];   const float* b2 = (const float*)d_in[8];
  const float* W3 = (const float*)d_in[9];   const float* b3 = (const float*)d_in[10];
  const float* WdIn = (const float*)d_in[11];  const float* bdin = (const float*)d_in[12];
  const float* WdOut = (const float*)d_in[13]; const float* bdout = (const float*)d_in[14];
  const float* W11 = (const float*)d_in[15]; const float* b11 = (const float*)d_in[16];
  const float* W12 = (const float*)d_in[17]; const float* b12 = (const float*)d_in[18];
  const float* W13 = (const float*)d_in[19]; const float* b13 = (const float*)d_in[20];
  const float* n1g = (const float*)d_in[21]; const float* n1b = (const float*)d_in[22];
  const float* n2g = (const float*)d_in[23]; const float* n2b = (const float*)d_in[24];
  const float* n3g = (const float*)d_in[25]; const float* n3b = (const float*)d_in[26];

  char* ws = (char*)d_ws;
  uint16_t* hVb    = (uint16_t*)(ws + 0);
  uint16_t* W1t    = (uint16_t*)(ws + 1048576);
  uint16_t* W2t    = (uint16_t*)(ws + 1146880);
  uint16_t* W3t    = (uint16_t*)(ws + 1179648);
  uint16_t* WdInT  = (uint16_t*)(ws + 1212416);
  uint16_t* WdOutT = (uint16_t*)(ws + 1343488);
  uint16_t* W11t   = (uint16_t*)(ws + 1474560);
  uint16_t* W12t   = (uint16_t*)(ws + 1572864);
  uint16_t* W13t   = (uint16_t*)(ws + 1605632);
  float*    hV1    = (float*)(ws + 1638400);
  uint16_t* hV1b   = (uint16_t*)(ws + 3735552);
  uint16_t* hV2b   = (uint16_t*)(ws + 4784128);
  float*    C1     = (float*)(ws + 5832704);
  float*    C2     = (float*)(ws + 7929856);
  uint16_t* hEb    = (uint16_t*)(ws + 10027008);  // 50,331,648 B if available

  const bool useB = (ws_size >= 10027008ull + 50331648ull);

  float* outV = (float*)d_out;
  float* outE = (float*)d_out + 524288;

  k_prep<<<3200, 256, 0, stream>>>(hV, W1, W2, W3, WdIn, WdOut, W11, W12, W13,
                                   hVb, W1t, W2t, W3t, WdInT, WdOutT, W11t, W12t, W13t);
  if (useB) k_prep2<<<12288, 256, 0, stream>>>(hE, hEb);
  k_vec<<<64, 256, 0, stream>>>(hVb, W1t, b1, C1);
  if (useB)
    k_node_t<true><<<2048, 256, 0, stream>>>(hV, hE, hEb, eidx, maskA, b2, b3,
                                             n1g, n1b, hVb, C1, W1t, W2t, W3t, hV1, hV1b);
  else
    k_node_t<false><<<2048, 256, 0, stream>>>(hV, hE, nullptr, eidx, maskA, b2, b3,
                                              n1g, n1b, hVb, C1, W1t, W2t, W3t, hV1, hV1b);
  k_ffn<<<256, 256, 0, stream>>>(hV1, hV1b, maskV, bdin, bdout, n2g, n2b,
                                 WdInT, WdOutT, outV, hV2b);
  k_vec<<<64, 256, 0, stream>>>(hV2b, W11t, b11, C2);
  if (useB)
    k_edge_t<true><<<2048, 256, 0, stream>>>(hE, hEb, eidx, b12, b13, n3g, n3b,
                                             hV2b, C2, W11t, W12t, W13t, outE);
  else
    k_edge_t<false><<<2048, 256, 0, stream>>>(hE, nullptr, eidx, b12, b13, n3g, n3b,
                                              hV2b, C2, W11t, W12t, W13t, outE);
}